// Round 4
// baseline (3659.301 us; speedup 1.0000x reference)
//
#include <hip/hip_runtime.h>
#include <hip/hip_fp16.h>

#define G_   20000
#define B_   256
#define NNZ_ 640000
#define KCH_ 640       // gemm1 split-K chunk (20 steps of 32; z=31 does 5)
#define NZ_  32        // split-K factor
#define NBUK 157       // ceil(20000/128) row buckets of 128 rows
#define BCAP 4608      // per-bucket segment capacity (avg 4076, >8 sigma slack)
#define EPB  4000      // binsort entries per block (160 blocks x 4000 = NNZ)

typedef float f4 __attribute__((ext_vector_type(4)));
typedef _Float16 h8 __attribute__((ext_vector_type(8)));

// ---------------- zero scratch ------------------------------------------
__global__ __launch_bounds__(256) void zero_kernel(unsigned int* p, int n) {
    int i = blockIdx.x * 256 + threadIdx.x;
    if (i < n) p[i] = 0u;
}

// ---------------- embed + transpose: [B,G] f32 -> [G,B] f16 --------------
__global__ __launch_bounds__(256) void embed_kernel(
        const float* __restrict__ xsamp, const float* __restrict__ xtf,
        const float* __restrict__ em, const float* __restrict__ bm,
        const float* __restrict__ ee, const float* __restrict__ be,
        __half* __restrict__ X0s, __half* __restrict__ X0t) {
    __shared__ float lds[64][65];       // [b][g]
    const int t  = threadIdx.x;
    const int gb = blockIdx.x * 64, bb = blockIdx.y * 64;
    const float a_m = em[0], c_m = bm[0], a_e = ee[0], c_e = be[0];
    const int gl = t & 63, brow0 = t >> 6;     // load mapping
    const int cl = t & 31, row0  = t >> 5;     // store mapping
    const int g_l = gb + gl;
#pragma unroll
    for (int r = 0; r < 16; r++) {
        int bl = brow0 + r * 4;
        float v = 0.f;
        if (g_l < G_) v = xsamp[(size_t)(bb + bl) * G_ + g_l];
        lds[bl][gl] = fmaxf(a_m * v + c_m, 0.f);
    }
    __syncthreads();
#pragma unroll
    for (int r = 0; r < 8; r++) {
        int gl2 = row0 + r * 8;
        int g = gb + gl2;
        if (g < G_) {
            __half2 hv = __floats2half2_rn(lds[cl * 2][gl2], lds[cl * 2 + 1][gl2]);
            *(__half2*)(X0s + (size_t)g * B_ + bb + cl * 2) = hv;
        }
    }
    __syncthreads();
#pragma unroll
    for (int r = 0; r < 16; r++) {
        int bl = brow0 + r * 4;
        float v = 0.f;
        if (g_l < G_) v = xtf[(size_t)(bb + bl) * G_ + g_l];
        lds[bl][gl] = fmaxf(a_e * v + c_e, 0.f);
    }
    __syncthreads();
#pragma unroll
    for (int r = 0; r < 8; r++) {
        int gl2 = row0 + r * 8;
        int g = gb + gl2;
        if (g < G_) {
            __half2 hv = __floats2half2_rn(lds[cl * 2][gl2], lds[cl * 2 + 1][gl2]);
            *(__half2*)(X0t + (size_t)g * B_ + bb + cl * 2) = hv;
        }
    }
}

// ---------------- bucket sort COO into 128-row bins ----------------------
// One dispatch replaces hist+scan+scatter. Per block: LDS histogram ->
// LDS scan -> stable place into LDS staging -> per-bucket global base via
// one atomicAdd -> coalesced run copy-out. meta.x = (rowInBucket<<24) |
// col*512 (byte offset); meta.y = f32 bits of 0.9*val (no extra quant).
__global__ __launch_bounds__(256) void binsort_kernel(
        const int* __restrict__ rA, const int* __restrict__ cA, const float* __restrict__ vA,
        const int* __restrict__ rB, const int* __restrict__ cB, const float* __restrict__ vB,
        int2* __restrict__ metaA, int* __restrict__ cntA,
        int2* __restrict__ metaB, int* __restrict__ cntB) {
    __shared__ int2 stage[EPB];                 // 32000 B
    __shared__ unsigned char bkid[EPB];         // 4000 B
    __shared__ int hist[NBUK], lstart[NBUK], gbase[NBUK];
    const int t = threadIdx.x;
    const int base = blockIdx.x * EPB;
    const int* rows; const int* colsp; const float* valsp; int2* meta; int* cnt;
    if (blockIdx.y == 0) { rows = rA; colsp = cA; valsp = vA; meta = metaA; cnt = cntA; }
    else                 { rows = rB; colsp = cB; valsp = vB; meta = metaB; cnt = cntB; }

    for (int i = t; i < NBUK; i += 256) hist[i] = 0;
    __syncthreads();
    // phase A: local histogram
    for (int i = t; i < EPB; i += 256)
        atomicAdd(&hist[rows[base + i] >> 7], 1);
    __syncthreads();
    // phase B: exclusive scan (157 elems, serial is cheap)
    if (t == 0) {
        int s = 0;
        for (int b = 0; b < NBUK; b++) { lstart[b] = s; s += hist[b]; }
    }
    __syncthreads();
    if (t < NBUK) hist[t] = lstart[t];          // reuse hist as cursor
    __syncthreads();
    // phase C: stable place into staging
    for (int i = t; i < EPB; i += 256) {
        int r = rows[base + i];
        int c = colsp[base + i];
        float v = valsp[base + i];
        int b = r >> 7;
        int p = atomicAdd(&hist[b], 1);
        stage[p] = make_int2(((r & 127) << 24) | (c * (B_ * 2)),
                             __float_as_int(0.9f * v));
        bkid[p] = (unsigned char)b;
    }
    __syncthreads();
    // phase D: one global atomic per bucket
    if (t < NBUK) gbase[t] = atomicAdd(&cnt[t], hist[t] - lstart[t]);
    __syncthreads();
    // phase E: coalesced run copy-out
    for (int i = t; i < EPB; i += 256) {
        int b = bkid[i];
        meta[(size_t)b * BCAP + gbase[b] + (i - lstart[b])] = stage[i];
    }
}

// ---------------- SPMM over buckets, LDS f32 tile accumulation -----------
// grid.x = NBUK*8; combo = bid&7 -> (chunk 0..3, matrix 0..1) so each XCD
// keeps one 2.56MB x-chunk L2-resident. Block 256 thr = 8 half-waves, each
// half-wave streams entries (stride 8); 32 lanes cover 64 cols via half2.
// Accumulate v*x into tile[128][64] f32 with LDS atomics; coalesced f16
// writeback. vals pre-scaled by 0.9 in binsort.
__global__ __launch_bounds__(256) void spmm_kernel(
        const int2* __restrict__ metaA, const int* __restrict__ cntA,
        const __half* __restrict__ xinA, __half* __restrict__ xoutA,
        const int2* __restrict__ metaB, const int* __restrict__ cntB,
        const __half* __restrict__ xinB, __half* __restrict__ xoutB) {
    __shared__ float tile[128][64];             // 32 KB
    const int bid   = blockIdx.x;
    const int combo = bid & 7;
    const int buk   = bid >> 3;
    const int chunk = combo & 3;
    const int t  = threadIdx.x;
    const int hw = t >> 5, cl = t & 31;
    const int2* meta; const int* cnt; const __half* xin; __half* xout;
    if (combo < 4) { meta = metaA; cnt = cntA; xin = xinA; xout = xoutA; }
    else           { meta = metaB; cnt = cntB; xin = xinB; xout = xoutB; }

    for (int i = t; i < 128 * 64 / 4; i += 256) ((f4*)tile)[i] = f4{0.f, 0.f, 0.f, 0.f};
    __syncthreads();

    const int nE = cnt[buk];
    const int2* mp = meta + (size_t)buk * BCAP;
    const char* xb = (const char*)xin + chunk * 128 + cl * 4;
    for (int e = hw; e < nE; e += 8) {
        int2 m = mp[e];
        int   row = (unsigned)m.x >> 24;
        int   off = m.x & 0xFFFFFF;
        float v   = __int_as_float(m.y);
        float2 x  = __half22float2(*(const __half2*)(xb + off));
        atomicAdd(&tile[row][cl * 2],     v * x.x);
        atomicAdd(&tile[row][cl * 2 + 1], v * x.y);
    }
    __syncthreads();

    const int g0 = buk * 128;
    const int nrows = min(128, G_ - g0);
    for (int r = hw; r < nrows; r += 8) {
        float2 p = *(const float2*)&tile[r][cl * 2];
        *(__half2*)((char*)xout + (size_t)(g0 + r) * (B_ * 2) + chunk * 128 + cl * 4) =
            __floats2half2_rn(p.x, p.y);
    }
}

// ---------------- combine + transpose + f16: -> had[b][g] ----------------
__global__ __launch_bounds__(256) void combine_kernel(
        const __half* __restrict__ X2s, const __half* __restrict__ X0s,
        const __half* __restrict__ X2t, const __half* __restrict__ X0t,
        __half* __restrict__ hadBK) {
    __shared__ float lds[64][65];       // [g][b]
    const int t = threadIdx.x;
    const int gb = blockIdx.x * 64, bb = blockIdx.y * 64;
    const int cl = t & 31, row0 = t >> 5;
#pragma unroll
    for (int r = 0; r < 8; r++) {
        int gl = row0 + r * 8;
        int g = gb + gl;
        float px = 0.f, py = 0.f;
        if (g < G_) {
            size_t idx = (size_t)g * B_ + bb + cl * 2;
            float2 x2s = __half22float2(*(const __half2*)(X2s + idx));
            float2 x0s = __half22float2(*(const __half2*)(X0s + idx));
            float2 x2t = __half22float2(*(const __half2*)(X2t + idx));
            float2 x0t = __half22float2(*(const __half2*)(X0t + idx));
            px = (x2s.x + 0.1f * x0s.x) * (x2t.x + 0.1f * x0t.x);
            py = (x2s.y + 0.1f * x0s.y) * (x2t.y + 0.1f * x0t.y);
        }
        lds[gl][cl * 2]     = px;
        lds[gl][cl * 2 + 1] = py;
    }
    __syncthreads();
#pragma unroll
    for (int r = 0; r < 8; r++) {
        int bl = row0 + r * 8;
        int g0 = gb + cl * 2;
        if (g0 < G_) {
            __half2 hv = __floats2half2_rn(lds[cl * 2][bl], lds[cl * 2 + 1][bl]);
            *(__half2*)(hadBK + (size_t)(bb + bl) * G_ + g0) = hv;
        }
    }
}

// ---------------- GEMM1 MFMA f16: part[z][b][o] --------------------------
// tile 256(b) x 128(o) x BK32, 512 thr = 8 waves (4 b-quads x 2 o-halves),
// W1 read as f32 and converted in staging (W1 read exactly once overall).
__global__ __launch_bounds__(512) void gemm1_kernel(
        const __half* __restrict__ hadBK, const float* __restrict__ W1,
        float* __restrict__ part) {
    __shared__ _Float16 a_lds[256][40];   // stride 80B = 16B-aligned, 2-way banks
    __shared__ _Float16 b_lds[128][40];
    const int t = threadIdx.x;
    const int lane = t & 63, wid = t >> 6;
    const int wm = wid >> 1, wn = wid & 1;
    const int l15 = lane & 15, l4 = lane >> 4;
    const int ob = blockIdx.x * 128;
    const int kb = blockIdx.y * KCH_;
    int kend = kb + KCH_; if (kend > G_) kend = G_;
    const int nsteps = (kend - kb) >> 5;       // 20, or 5 at z=31
    const int ar = t >> 1, ah = t & 1;
    const int br = t >> 2, bs = t & 3;
    const _Float16* hadH = (const _Float16*)hadBK;
    f4 acc[4][4] = {};
    for (int s = 0; s < nsteps; ++s) {
        const int k0 = kb + s * 32;
        {   // stage A: hadBK rows (b)
            const _Float16* src = hadH + (size_t)ar * G_ + k0 + ah * 16;
            *(h8*)&a_lds[ar][ah * 16]     = *(const h8*)(src);
            *(h8*)&a_lds[ar][ah * 16 + 8] = *(const h8*)(src + 8);
        }
        {   // stage B: W1 f32 rows (o), convert to f16
            const float* src = W1 + (size_t)(ob + br) * G_ + k0 + bs * 8;
            f4 w0 = *(const f4*)src;
            f4 w1 = *(const f4*)(src + 4);
            h8 h;
            h[0] = (_Float16)w0[0]; h[1] = (_Float16)w0[1];
            h[2] = (_Float16)w0[2]; h[3] = (_Float16)w0[3];
            h[4] = (_Float16)w1[0]; h[5] = (_Float16)w1[1];
            h[6] = (_Float16)w1[2]; h[7] = (_Float16)w1[3];
            *(h8*)&b_lds[br][bs * 8] = h;
        }
        __syncthreads();
        h8 af[4], bf[4];
#pragma unroll
        for (int m = 0; m < 4; m++)
            af[m] = *(const h8*)&a_lds[wm * 64 + m * 16 + l15][l4 * 8];
#pragma unroll
        for (int n = 0; n < 4; n++)
            bf[n] = *(const h8*)&b_lds[wn * 64 + n * 16 + l15][l4 * 8];
#pragma unroll
        for (int m = 0; m < 4; m++)
#pragma unroll
            for (int n = 0; n < 4; n++)
                acc[m][n] = __builtin_amdgcn_mfma_f32_16x16x32_f16(
                    af[m], bf[n], acc[m][n], 0, 0, 0);
        __syncthreads();
    }
    const size_t zoff = (size_t)blockIdx.y * (B_ * 1024);
#pragma unroll
    for (int m = 0; m < 4; m++)
#pragma unroll
        for (int n = 0; n < 4; n++)
#pragma unroll
            for (int j = 0; j < 4; j++) {
                int b = wm * 64 + m * 16 + l4 * 4 + j;
                int o = ob + wn * 64 + n * 16 + l15;
                part[zoff + (size_t)b * 1024 + o] = acc[m][n][j];
            }
}

// ---------------- reduce split-K + bias + relu -> h1 ---------------------
__global__ __launch_bounds__(256) void reduce_kernel(
        const float* __restrict__ part, const float* __restrict__ b1,
        float* __restrict__ h1) {
    int i = blockIdx.x * 256 + threadIdx.x;    // 262144 total
    float s = 0.f;
#pragma unroll
    for (int z = 0; z < NZ_; z++) s += part[(size_t)z * 262144 + i];
    h1[i] = fmaxf(s + b1[i & 1023], 0.f);
}

// ---------------- fused GEMM2 (relu) + GEMM3 -----------------------------
__global__ __launch_bounds__(128) void gemm23_kernel(
        const float* __restrict__ h1, const float* __restrict__ W2,
        const float* __restrict__ b2, const float* __restrict__ W3,
        const float* __restrict__ b3, float* __restrict__ out) {
    __shared__ float h1row[1024];
    __shared__ float h2[128];
    const int b = blockIdx.x, t = threadIdx.x;
    *(f4*)&h1row[t * 4]       = *(const f4*)(h1 + (size_t)b * 1024 + t * 4);
    *(f4*)&h1row[512 + t * 4] = *(const f4*)(h1 + (size_t)b * 1024 + 512 + t * 4);
    __syncthreads();
    {
        float acc = b2[t];
        const f4* w  = (const f4*)(W2 + (size_t)t * 1024);
        const f4* hr = (const f4*)h1row;
        for (int k = 0; k < 256; k++) {
            f4 wv = w[k], hv = hr[k];
            acc += wv[0] * hv[0] + wv[1] * hv[1] + wv[2] * hv[2] + wv[3] * hv[3];
        }
        h2[t] = fmaxf(acc, 0.f);
    }
    __syncthreads();
    if (t < 33) {
        float acc = b3[t];
        const f4* w  = (const f4*)(W3 + (size_t)t * 128);
        const f4* hv = (const f4*)h2;
#pragma unroll
        for (int k = 0; k < 32; k++) {
            f4 a = w[k], x = hv[k];
            acc += a[0] * x[0] + a[1] * x[1] + a[2] * x[2] + a[3] * x[3];
        }
        out[b * 33 + t] = acc;
    }
}

extern "C" void kernel_launch(void* const* d_in, const int* in_sizes, int n_in,
                              void* d_out, int out_size, void* d_ws, size_t ws_size,
                              hipStream_t stream) {
    const float* x_sample  = (const float*)d_in[0];
    const float* x_TF      = (const float*)d_in[1];
    const int*   adj_rows  = (const int*)d_in[2];
    const int*   adj_cols  = (const int*)d_in[3];
    const float* adj_vals  = (const float*)d_in[4];
    const int*   adjT_rows = (const int*)d_in[5];
    const int*   adjT_cols = (const int*)d_in[6];
    const float* adjT_vals = (const float*)d_in[7];
    const float* emb_mut   = (const float*)d_in[8];
    const float* bias_mut  = (const float*)d_in[9];
    const float* emb_exp   = (const float*)d_in[10];
    const float* bias_exp  = (const float*)d_in[11];
    const float* W1 = (const float*)d_in[12];
    const float* b1 = (const float*)d_in[13];
    const float* W2 = (const float*)d_in[14];
    const float* b2 = (const float*)d_in[15];
    const float* W3 = (const float*)d_in[16];
    const float* b3 = (const float*)d_in[17];
    float* out = (float*)d_out;

    // ---- workspace layout (~108 MB) ----
    char* w = (char*)d_ws;
    auto alloc = [&](size_t bytes) {
        char* p = w; w += (bytes + 255) & ~(size_t)255; return p;
    };
    __half* X0s = (__half*)alloc(5120000 * 2);
    __half* X1s = (__half*)alloc(5120000 * 2);
    __half* X2s = (__half*)alloc(5120000 * 2);
    __half* X0t = (__half*)alloc(5120000 * 2);
    __half* X1t = (__half*)alloc(5120000 * 2);
    __half* X2t = (__half*)alloc(5120000 * 2);
    float*  part = (float*)alloc((size_t)NZ_ * 262144 * 4);   // 33.5 MB
    float*  h1   = (float*)alloc(262144 * 4);
    int2*   metaA = (int2*)alloc((size_t)NBUK * BCAP * 8);    // 5.79 MB
    int2*   metaB = (int2*)alloc((size_t)NBUK * BCAP * 8);
    int*    cnt   = (int*)alloc(2 * NBUK * 4);
    int*    cntA  = cnt;
    int*    cntB  = cnt + NBUK;
    __half* hadBK = X1s;    // overlay: X1s dead after spmm iter 2

    zero_kernel<<<2, 256, 0, stream>>>((unsigned int*)cnt, 2 * NBUK);

    embed_kernel<<<dim3(313, 4), 256, 0, stream>>>(
        x_sample, x_TF, emb_mut, bias_mut, emb_exp, bias_exp, X0s, X0t);

    // bucket-sort both COO matrices (replaces hist+scan+scatter)
    binsort_kernel<<<dim3(160, 2), 256, 0, stream>>>(
        adj_rows, adj_cols, adj_vals, adjT_rows, adjT_cols, adjT_vals,
        metaA, cntA, metaB, cntB);

    // K = 2 PPR iterations (0.9 folded into vals)
    spmm_kernel<<<NBUK * 8, 256, 0, stream>>>(metaA, cntA, X0s, X1s,
                                              metaB, cntB, X0t, X1t);
    spmm_kernel<<<NBUK * 8, 256, 0, stream>>>(metaA, cntA, X1s, X2s,
                                              metaB, cntB, X1t, X2t);

    combine_kernel<<<dim3(313, 4), 256, 0, stream>>>(X2s, X0s, X2t, X0t, hadBK);

    gemm1_kernel<<<dim3(8, NZ_), 512, 0, stream>>>(hadBK, W1, part);
    reduce_kernel<<<1024, 256, 0, stream>>>(part, b1, h1);
    gemm23_kernel<<<B_, 128, 0, stream>>>(h1, W2, b2, W3, b3, out);
}

// Round 5
// 474.474 us; speedup vs baseline: 7.7123x; 7.7123x over previous
//
#include <hip/hip_runtime.h>
#include <hip/hip_fp16.h>

#define G_   20000
#define B_   256
#define NNZ_ 640000
#define KCH_ 640       // gemm1 split-K chunk (20 steps of 32; z=31 does 5)
#define NZ_  32        // split-K factor
#define NBUK 157       // ceil(20000/128) row buckets of 128 rows
#define BCAP 4608      // per-bucket segment capacity (avg 4076, >8 sigma slack)
#define EPB  4000      // binsort entries per block (160 blocks x 4000 = NNZ)

typedef float f4 __attribute__((ext_vector_type(4)));
typedef _Float16 h8 __attribute__((ext_vector_type(8)));

// ---------------- zero scratch ------------------------------------------
__global__ __launch_bounds__(256) void zero_kernel(unsigned int* p, int n) {
    int i = blockIdx.x * 256 + threadIdx.x;
    if (i < n) p[i] = 0u;
}

// zero the sorted-meta padding tails (128 int2 each) so lockstep spmm
// overrun reads are harmless (v predicated to 0, offset 0 is valid)
__global__ __launch_bounds__(256) void pad_kernel(int* pA, int* pB) {
    int t = threadIdx.x;
    pA[t] = 0; pB[t] = 0;
}

// ---------------- embed + transpose: [B,G] f32 -> [G,B] f16 --------------
__global__ __launch_bounds__(256) void embed_kernel(
        const float* __restrict__ xsamp, const float* __restrict__ xtf,
        const float* __restrict__ em, const float* __restrict__ bm,
        const float* __restrict__ ee, const float* __restrict__ be,
        __half* __restrict__ X0s, __half* __restrict__ X0t) {
    __shared__ float lds[64][65];       // [b][g]
    const int t  = threadIdx.x;
    const int gb = blockIdx.x * 64, bb = blockIdx.y * 64;
    const float a_m = em[0], c_m = bm[0], a_e = ee[0], c_e = be[0];
    const int gl = t & 63, brow0 = t >> 6;     // load mapping
    const int cl = t & 31, row0  = t >> 5;     // store mapping
    const int g_l = gb + gl;
#pragma unroll
    for (int r = 0; r < 16; r++) {
        int bl = brow0 + r * 4;
        float v = 0.f;
        if (g_l < G_) v = xsamp[(size_t)(bb + bl) * G_ + g_l];
        lds[bl][gl] = fmaxf(a_m * v + c_m, 0.f);
    }
    __syncthreads();
#pragma unroll
    for (int r = 0; r < 8; r++) {
        int gl2 = row0 + r * 8;
        int g = gb + gl2;
        if (g < G_) {
            __half2 hv = __floats2half2_rn(lds[cl * 2][gl2], lds[cl * 2 + 1][gl2]);
            *(__half2*)(X0s + (size_t)g * B_ + bb + cl * 2) = hv;
        }
    }
    __syncthreads();
#pragma unroll
    for (int r = 0; r < 16; r++) {
        int bl = brow0 + r * 4;
        float v = 0.f;
        if (g_l < G_) v = xtf[(size_t)(bb + bl) * G_ + g_l];
        lds[bl][gl] = fmaxf(a_e * v + c_e, 0.f);
    }
    __syncthreads();
#pragma unroll
    for (int r = 0; r < 8; r++) {
        int gl2 = row0 + r * 8;
        int g = gb + gl2;
        if (g < G_) {
            __half2 hv = __floats2half2_rn(lds[cl * 2][gl2], lds[cl * 2 + 1][gl2]);
            *(__half2*)(X0t + (size_t)g * B_ + bb + cl * 2) = hv;
        }
    }
}

// ---------------- pass 1: bucket sort COO into 128-row bins --------------
// Per block: LDS histogram -> LDS scan -> stable place into LDS staging ->
// one global atomicAdd per bucket -> coalesced run copy-out.
// meta.x = (rowInBucket<<24) | col*512 ; meta.y = f32 bits of 0.9*val.
__global__ __launch_bounds__(256) void binsort_kernel(
        const int* __restrict__ rA, const int* __restrict__ cA, const float* __restrict__ vA,
        const int* __restrict__ rB, const int* __restrict__ cB, const float* __restrict__ vB,
        int2* __restrict__ metaA, int* __restrict__ cntA,
        int2* __restrict__ metaB, int* __restrict__ cntB) {
    __shared__ int2 stage[EPB];                 // 32000 B
    __shared__ unsigned char bkid[EPB];         // 4000 B
    __shared__ int hist[NBUK], lstart[NBUK], gbase[NBUK];
    const int t = threadIdx.x;
    const int base = blockIdx.x * EPB;
    const int* rows; const int* colsp; const float* valsp; int2* meta; int* cnt;
    if (blockIdx.y == 0) { rows = rA; colsp = cA; valsp = vA; meta = metaA; cnt = cntA; }
    else                 { rows = rB; colsp = cB; valsp = vB; meta = metaB; cnt = cntB; }

    for (int i = t; i < NBUK; i += 256) hist[i] = 0;
    __syncthreads();
    for (int i = t; i < EPB; i += 256)
        atomicAdd(&hist[rows[base + i] >> 7], 1);
    __syncthreads();
    if (t == 0) {
        int s = 0;
        for (int b = 0; b < NBUK; b++) { lstart[b] = s; s += hist[b]; }
    }
    __syncthreads();
    if (t < NBUK) hist[t] = lstart[t];          // reuse hist as cursor
    __syncthreads();
    for (int i = t; i < EPB; i += 256) {
        int r = rows[base + i];
        int c = colsp[base + i];
        float v = valsp[base + i];
        int b = r >> 7;
        int p = atomicAdd(&hist[b], 1);
        stage[p] = make_int2(((r & 127) << 24) | (c * (B_ * 2)),
                             __float_as_int(0.9f * v));
        bkid[p] = (unsigned char)b;
    }
    __syncthreads();
    if (t < NBUK) gbase[t] = atomicAdd(&cnt[t], hist[t] - lstart[t]);
    __syncthreads();
    for (int i = t; i < EPB; i += 256) {
        int b = bkid[i];
        meta[(size_t)b * BCAP + gbase[b] + (i - lstart[b])] = stage[i];
    }
}

// ---------------- pass 2: in-bucket counting sort -> exact CSR -----------
// One block per (bucket, matrix). Load bucket segment to LDS, counting-sort
// by the 128 in-bucket rows, write coalesced sorted run + row pointers.
__global__ __launch_bounds__(256) void rowsort_kernel(
        const int2* __restrict__ metaA, const int* __restrict__ cntA,
        int2* __restrict__ sortedA, int* __restrict__ rpA,
        const int2* __restrict__ metaB, const int* __restrict__ cntB,
        int2* __restrict__ sortedB, int* __restrict__ rpB) {
    __shared__ int2 stage[BCAP];                // 36864 B
    __shared__ int2 sorted[BCAP];               // 36864 B
    __shared__ int carr[NBUK];
    __shared__ int hist[128], lstart[128];
    const int t = threadIdx.x;
    const int buk = blockIdx.x;
    const int2* meta; const int* cnt; int2* outp; int* rp;
    if (blockIdx.y == 0) { meta = metaA; cnt = cntA; outp = sortedA; rp = rpA; }
    else                 { meta = metaB; cnt = cntB; outp = sortedB; rp = rpB; }

    if (t < NBUK) carr[t] = cnt[t];
    if (t < 128) hist[t] = 0;
    __syncthreads();
    int bukStart = 0, nE = carr[buk];
    // serial prefix in LDS is cheap; every thread computes it redundantly
    for (int b = 0; b < NBUK; b++) bukStart += (b < buk) ? carr[b] : 0;

    const int2* mp = meta + (size_t)buk * BCAP;
    for (int i = t; i < nE; i += 256) {
        int2 m = mp[i];
        stage[i] = m;
        atomicAdd(&hist[(unsigned)m.x >> 24], 1);
    }
    __syncthreads();
    if (t == 0) {
        int s = 0;
        for (int r = 0; r < 128; r++) { lstart[r] = s; s += hist[r]; }
    }
    __syncthreads();
    if (t < 128) hist[t] = lstart[t];           // reuse as cursor
    __syncthreads();
    for (int i = t; i < nE; i += 256) {
        int2 m = stage[i];
        int r = (unsigned)m.x >> 24;
        int p = atomicAdd(&hist[r], 1);
        sorted[p] = make_int2(m.x & 0xFFFFFF, m.y);
    }
    __syncthreads();
    for (int i = t; i < nE; i += 256)
        outp[bukStart + i] = sorted[i];
    if (t < 128) {
        int g = buk * 128 + t;
        if (g < G_) rp[g] = bukStart + lstart[t];
    }
    if (buk == NBUK - 1 && t == 0) rp[G_] = bukStart + nE;
}

// ---------------- SPMM f16, 64-col chunks, XCD-affine (round-3 proven) ---
__global__ __launch_bounds__(256) void spmm_kernel(
        const int* __restrict__ rpA, const int2* __restrict__ metaA,
        const __half* __restrict__ xinA, __half* __restrict__ xoutA,
        const int* __restrict__ rpB, const int2* __restrict__ metaB,
        const __half* __restrict__ xinB, __half* __restrict__ xoutB) {
    const int bid   = blockIdx.x;
    const int combo = bid & 7;
    const int rowblk = bid >> 3;
    const int chunk = combo & 3;
    const int t = threadIdx.x;
    const int wave = t >> 6, lane = t & 63;
    const int half = lane >> 5, cl = lane & 31;
    const int g = rowblk * 8 + wave * 2 + half;
    const int loff = chunk * 128 + cl * 4;       // byte offset within x row
    const int* rp; const int2* meta; const __half* xin; __half* xout;
    if (combo < 4) { rp = rpA; meta = metaA; xin = xinA; xout = xoutA; }
    else           { rp = rpB; meta = metaB; xin = xinB; xout = xoutB; }
    int beg = rp[g];
    int n   = rp[g + 1] - beg;
    int nother = __shfl_xor(n, 32);
    int nmax = n > nother ? n : nother;
    const char* xb = (const char*)xin + loff;
    float ax = 0.f, ay = 0.f;
    int e = 0;
    for (; e + 4 <= nmax; e += 4) {
        int2 m0 = meta[beg + e],     m1 = meta[beg + e + 1];
        int2 m2 = meta[beg + e + 2], m3 = meta[beg + e + 3];
        float v0 = (e + 0 < n) ? __int_as_float(m0.y) : 0.f;
        float v1 = (e + 1 < n) ? __int_as_float(m1.y) : 0.f;
        float v2 = (e + 2 < n) ? __int_as_float(m2.y) : 0.f;
        float v3 = (e + 3 < n) ? __int_as_float(m3.y) : 0.f;
        float2 x0 = __half22float2(*(const __half2*)(xb + m0.x));
        float2 x1 = __half22float2(*(const __half2*)(xb + m1.x));
        float2 x2 = __half22float2(*(const __half2*)(xb + m2.x));
        float2 x3 = __half22float2(*(const __half2*)(xb + m3.x));
        ax = fmaf(v0, x0.x, ax); ay = fmaf(v0, x0.y, ay);
        ax = fmaf(v1, x1.x, ax); ay = fmaf(v1, x1.y, ay);
        ax = fmaf(v2, x2.x, ax); ay = fmaf(v2, x2.y, ay);
        ax = fmaf(v3, x3.x, ax); ay = fmaf(v3, x3.y, ay);
    }
    for (; e < nmax; ++e) {
        int2 m = meta[beg + e];
        float v = (e < n) ? __int_as_float(m.y) : 0.f;
        float2 x = __half22float2(*(const __half2*)(xb + m.x));
        ax = fmaf(v, x.x, ax); ay = fmaf(v, x.y, ay);
    }
    *(__half2*)((char*)xout + (size_t)g * (B_ * 2) + loff) = __floats2half2_rn(ax, ay);
}

// ---------------- combine + transpose + f16: -> had[b][g] ----------------
__global__ __launch_bounds__(256) void combine_kernel(
        const __half* __restrict__ X2s, const __half* __restrict__ X0s,
        const __half* __restrict__ X2t, const __half* __restrict__ X0t,
        __half* __restrict__ hadBK) {
    __shared__ float lds[64][65];       // [g][b]
    const int t = threadIdx.x;
    const int gb = blockIdx.x * 64, bb = blockIdx.y * 64;
    const int cl = t & 31, row0 = t >> 5;
#pragma unroll
    for (int r = 0; r < 8; r++) {
        int gl = row0 + r * 8;
        int g = gb + gl;
        float px = 0.f, py = 0.f;
        if (g < G_) {
            size_t idx = (size_t)g * B_ + bb + cl * 2;
            float2 x2s = __half22float2(*(const __half2*)(X2s + idx));
            float2 x0s = __half22float2(*(const __half2*)(X0s + idx));
            float2 x2t = __half22float2(*(const __half2*)(X2t + idx));
            float2 x0t = __half22float2(*(const __half2*)(X0t + idx));
            px = (x2s.x + 0.1f * x0s.x) * (x2t.x + 0.1f * x0t.x);
            py = (x2s.y + 0.1f * x0s.y) * (x2t.y + 0.1f * x0t.y);
        }
        lds[gl][cl * 2]     = px;
        lds[gl][cl * 2 + 1] = py;
    }
    __syncthreads();
#pragma unroll
    for (int r = 0; r < 8; r++) {
        int bl = row0 + r * 8;
        int g0 = gb + cl * 2;
        if (g0 < G_) {
            __half2 hv = __floats2half2_rn(lds[cl * 2][bl], lds[cl * 2 + 1][bl]);
            *(__half2*)(hadBK + (size_t)(bb + bl) * G_ + g0) = hv;
        }
    }
}

// ---------------- GEMM1 MFMA f16: part[z][b][o] --------------------------
__global__ __launch_bounds__(512) void gemm1_kernel(
        const __half* __restrict__ hadBK, const float* __restrict__ W1,
        float* __restrict__ part) {
    __shared__ _Float16 a_lds[256][40];   // stride 80B = 16B-aligned, 2-way banks
    __shared__ _Float16 b_lds[128][40];
    const int t = threadIdx.x;
    const int lane = t & 63, wid = t >> 6;
    const int wm = wid >> 1, wn = wid & 1;
    const int l15 = lane & 15, l4 = lane >> 4;
    const int ob = blockIdx.x * 128;
    const int kb = blockIdx.y * KCH_;
    int kend = kb + KCH_; if (kend > G_) kend = G_;
    const int nsteps = (kend - kb) >> 5;       // 20, or 5 at z=31
    const int ar = t >> 1, ah = t & 1;
    const int br = t >> 2, bs = t & 3;
    const _Float16* hadH = (const _Float16*)hadBK;
    f4 acc[4][4] = {};
    for (int s = 0; s < nsteps; ++s) {
        const int k0 = kb + s * 32;
        {   // stage A: hadBK rows (b)
            const _Float16* src = hadH + (size_t)ar * G_ + k0 + ah * 16;
            *(h8*)&a_lds[ar][ah * 16]     = *(const h8*)(src);
            *(h8*)&a_lds[ar][ah * 16 + 8] = *(const h8*)(src + 8);
        }
        {   // stage B: W1 f32 rows (o), convert to f16
            const float* src = W1 + (size_t)(ob + br) * G_ + k0 + bs * 8;
            f4 w0 = *(const f4*)src;
            f4 w1 = *(const f4*)(src + 4);
            h8 h;
            h[0] = (_Float16)w0[0]; h[1] = (_Float16)w0[1];
            h[2] = (_Float16)w0[2]; h[3] = (_Float16)w0[3];
            h[4] = (_Float16)w1[0]; h[5] = (_Float16)w1[1];
            h[6] = (_Float16)w1[2]; h[7] = (_Float16)w1[3];
            *(h8*)&b_lds[br][bs * 8] = h;
        }
        __syncthreads();
        h8 af[4], bf[4];
#pragma unroll
        for (int m = 0; m < 4; m++)
            af[m] = *(const h8*)&a_lds[wm * 64 + m * 16 + l15][l4 * 8];
#pragma unroll
        for (int n = 0; n < 4; n++)
            bf[n] = *(const h8*)&b_lds[wn * 64 + n * 16 + l15][l4 * 8];
#pragma unroll
        for (int m = 0; m < 4; m++)
#pragma unroll
            for (int n = 0; n < 4; n++)
                acc[m][n] = __builtin_amdgcn_mfma_f32_16x16x32_f16(
                    af[m], bf[n], acc[m][n], 0, 0, 0);
        __syncthreads();
    }
    const size_t zoff = (size_t)blockIdx.y * (B_ * 1024);
#pragma unroll
    for (int m = 0; m < 4; m++)
#pragma unroll
        for (int n = 0; n < 4; n++)
#pragma unroll
            for (int j = 0; j < 4; j++) {
                int b = wm * 64 + m * 16 + l4 * 4 + j;
                int o = ob + wn * 64 + n * 16 + l15;
                part[zoff + (size_t)b * 1024 + o] = acc[m][n][j];
            }
}

// ---------------- reduce split-K + bias + relu -> h1 ---------------------
__global__ __launch_bounds__(256) void reduce_kernel(
        const float* __restrict__ part, const float* __restrict__ b1,
        float* __restrict__ h1) {
    int i = blockIdx.x * 256 + threadIdx.x;    // 262144 total
    float s = 0.f;
#pragma unroll
    for (int z = 0; z < NZ_; z++) s += part[(size_t)z * 262144 + i];
    h1[i] = fmaxf(s + b1[i & 1023], 0.f);
}

// ---------------- fused GEMM2 (relu) + GEMM3 -----------------------------
__global__ __launch_bounds__(128) void gemm23_kernel(
        const float* __restrict__ h1, const float* __restrict__ W2,
        const float* __restrict__ b2, const float* __restrict__ W3,
        const float* __restrict__ b3, float* __restrict__ out) {
    __shared__ float h1row[1024];
    __shared__ float h2[128];
    const int b = blockIdx.x, t = threadIdx.x;
    *(f4*)&h1row[t * 4]       = *(const f4*)(h1 + (size_t)b * 1024 + t * 4);
    *(f4*)&h1row[512 + t * 4] = *(const f4*)(h1 + (size_t)b * 1024 + 512 + t * 4);
    __syncthreads();
    {
        float acc = b2[t];
        const f4* w  = (const f4*)(W2 + (size_t)t * 1024);
        const f4* hr = (const f4*)h1row;
        for (int k = 0; k < 256; k++) {
            f4 wv = w[k], hv = hr[k];
            acc += wv[0] * hv[0] + wv[1] * hv[1] + wv[2] * hv[2] + wv[3] * hv[3];
        }
        h2[t] = fmaxf(acc, 0.f);
    }
    __syncthreads();
    if (t < 33) {
        float acc = b3[t];
        const f4* w  = (const f4*)(W3 + (size_t)t * 128);
        const f4* hv = (const f4*)h2;
#pragma unroll
        for (int k = 0; k < 32; k++) {
            f4 a = w[k], x = hv[k];
            acc += a[0] * x[0] + a[1] * x[1] + a[2] * x[2] + a[3] * x[3];
        }
        out[b * 33 + t] = acc;
    }
}

extern "C" void kernel_launch(void* const* d_in, const int* in_sizes, int n_in,
                              void* d_out, int out_size, void* d_ws, size_t ws_size,
                              hipStream_t stream) {
    const float* x_sample  = (const float*)d_in[0];
    const float* x_TF      = (const float*)d_in[1];
    const int*   adj_rows  = (const int*)d_in[2];
    const int*   adj_cols  = (const int*)d_in[3];
    const float* adj_vals  = (const float*)d_in[4];
    const int*   adjT_rows = (const int*)d_in[5];
    const int*   adjT_cols = (const int*)d_in[6];
    const float* adjT_vals = (const float*)d_in[7];
    const float* emb_mut   = (const float*)d_in[8];
    const float* bias_mut  = (const float*)d_in[9];
    const float* emb_exp   = (const float*)d_in[10];
    const float* bias_exp  = (const float*)d_in[11];
    const float* W1 = (const float*)d_in[12];
    const float* b1 = (const float*)d_in[13];
    const float* W2 = (const float*)d_in[14];
    const float* b2 = (const float*)d_in[15];
    const float* W3 = (const float*)d_in[16];
    const float* b3 = (const float*)d_in[17];
    float* out = (float*)d_out;

    // ---- workspace layout (~120 MB) ----
    char* w = (char*)d_ws;
    auto alloc = [&](size_t bytes) {
        char* p = w; w += (bytes + 255) & ~(size_t)255; return p;
    };
    __half* X0s = (__half*)alloc(5120000 * 2);
    __half* X1s = (__half*)alloc(5120000 * 2);
    __half* X2s = (__half*)alloc(5120000 * 2);
    __half* X0t = (__half*)alloc(5120000 * 2);
    __half* X1t = (__half*)alloc(5120000 * 2);
    __half* X2t = (__half*)alloc(5120000 * 2);
    float*  part = (float*)alloc((size_t)NZ_ * 262144 * 4);   // 33.5 MB
    float*  h1   = (float*)alloc(262144 * 4);
    int2*   metaA   = (int2*)alloc((size_t)NBUK * BCAP * 8);  // 5.79 MB bucketed
    int2*   metaB   = (int2*)alloc((size_t)NBUK * BCAP * 8);
    int2*   sortedA = (int2*)alloc((size_t)(NNZ_ + 128) * 8); // 5.12 MB CSR-sorted
    int2*   sortedB = (int2*)alloc((size_t)(NNZ_ + 128) * 8);
    int*    cnt   = (int*)alloc(2 * NBUK * 4);
    int*    cntA  = cnt;
    int*    cntB  = cnt + NBUK;
    int*    rpA   = (int*)alloc(20001 * 4);
    int*    rpB   = (int*)alloc(20001 * 4);
    __half* hadBK = X1s;    // overlay: X1s dead after spmm iter 2

    zero_kernel<<<2, 256, 0, stream>>>((unsigned int*)cnt, 2 * NBUK);
    pad_kernel<<<1, 256, 0, stream>>>((int*)(sortedA + NNZ_), (int*)(sortedB + NNZ_));

    embed_kernel<<<dim3(313, 4), 256, 0, stream>>>(
        x_sample, x_TF, emb_mut, bias_mut, emb_exp, bias_exp, X0s, X0t);

    // two-pass coalesced CSR build
    binsort_kernel<<<dim3(160, 2), 256, 0, stream>>>(
        adj_rows, adj_cols, adj_vals, adjT_rows, adjT_cols, adjT_vals,
        metaA, cntA, metaB, cntB);
    rowsort_kernel<<<dim3(NBUK, 2), 256, 0, stream>>>(
        metaA, cntA, sortedA, rpA, metaB, cntB, sortedB, rpB);

    // K = 2 PPR iterations (0.9 folded into vals)
    spmm_kernel<<<20000, 256, 0, stream>>>(rpA, sortedA, X0s, X1s,
                                           rpB, sortedB, X0t, X1t);
    spmm_kernel<<<20000, 256, 0, stream>>>(rpA, sortedA, X1s, X2s,
                                           rpB, sortedB, X1t, X2t);

    combine_kernel<<<dim3(313, 4), 256, 0, stream>>>(X2s, X0s, X2t, X0t, hadBK);

    gemm1_kernel<<<dim3(8, NZ_), 512, 0, stream>>>(hadBK, W1, part);
    reduce_kernel<<<1024, 256, 0, stream>>>(part, b1, h1);
    gemm23_kernel<<<B_, 128, 0, stream>>>(h1, W2, b2, W3, b3, out);
}

// Round 6
// 445.770 us; speedup vs baseline: 8.2089x; 1.0644x over previous
//
#include <hip/hip_runtime.h>
#include <hip/hip_fp16.h>

#define G_   20000
#define B_   256
#define NNZ_ 640000
#define KCH_ 640       // gemm1 split-K chunk (20 steps of 32; z=31 does 5)
#define NZ_  32        // split-K factor
#define NBUK 157       // ceil(20000/128) row buckets of 128 rows
#define BCAP 4608      // per-bucket segment capacity (avg 4076, >8 sigma slack)
#define EPB  4000      // binsort entries per block (160 blocks x 4000 = NNZ)

typedef float f4 __attribute__((ext_vector_type(4)));
typedef _Float16 h8 __attribute__((ext_vector_type(8)));

// ---------------- zero scratch ------------------------------------------
__global__ __launch_bounds__(256) void zero_kernel(unsigned int* p, int n) {
    int i = blockIdx.x * 256 + threadIdx.x;
    if (i < n) p[i] = 0u;
}

// ---------------- embed + transpose: [B,G] f32 -> [G,B] f16 --------------
__global__ __launch_bounds__(256) void embed_kernel(
        const float* __restrict__ xsamp, const float* __restrict__ xtf,
        const float* __restrict__ em, const float* __restrict__ bm,
        const float* __restrict__ ee, const float* __restrict__ be,
        __half* __restrict__ X0s, __half* __restrict__ X0t) {
    __shared__ float lds[64][65];       // [b][g]
    const int t  = threadIdx.x;
    const int gb = blockIdx.x * 64, bb = blockIdx.y * 64;
    const float a_m = em[0], c_m = bm[0], a_e = ee[0], c_e = be[0];
    const int gl = t & 63, brow0 = t >> 6;     // load mapping
    const int cl = t & 31, row0  = t >> 5;     // store mapping
    const int g_l = gb + gl;
#pragma unroll
    for (int r = 0; r < 16; r++) {
        int bl = brow0 + r * 4;
        float v = 0.f;
        if (g_l < G_) v = xsamp[(size_t)(bb + bl) * G_ + g_l];
        lds[bl][gl] = fmaxf(a_m * v + c_m, 0.f);
    }
    __syncthreads();
#pragma unroll
    for (int r = 0; r < 8; r++) {
        int gl2 = row0 + r * 8;
        int g = gb + gl2;
        if (g < G_) {
            __half2 hv = __floats2half2_rn(lds[cl * 2][gl2], lds[cl * 2 + 1][gl2]);
            *(__half2*)(X0s + (size_t)g * B_ + bb + cl * 2) = hv;
        }
    }
    __syncthreads();
#pragma unroll
    for (int r = 0; r < 16; r++) {
        int bl = brow0 + r * 4;
        float v = 0.f;
        if (g_l < G_) v = xtf[(size_t)(bb + bl) * G_ + g_l];
        lds[bl][gl] = fmaxf(a_e * v + c_e, 0.f);
    }
    __syncthreads();
#pragma unroll
    for (int r = 0; r < 8; r++) {
        int gl2 = row0 + r * 8;
        int g = gb + gl2;
        if (g < G_) {
            __half2 hv = __floats2half2_rn(lds[cl * 2][gl2], lds[cl * 2 + 1][gl2]);
            *(__half2*)(X0t + (size_t)g * B_ + bb + cl * 2) = hv;
        }
    }
}

// ---------------- pass 1: bucket sort COO into 128-row bins --------------
// meta.x = (rowInBucket<<24) | col*512 ; meta.y = f32 bits of 0.9*val.
__global__ __launch_bounds__(256) void binsort_kernel(
        const int* __restrict__ rA, const int* __restrict__ cA, const float* __restrict__ vA,
        const int* __restrict__ rB, const int* __restrict__ cB, const float* __restrict__ vB,
        int2* __restrict__ metaA, int* __restrict__ cntA,
        int2* __restrict__ metaB, int* __restrict__ cntB) {
    __shared__ int2 stage[EPB];                 // 32000 B
    __shared__ unsigned char bkid[EPB];         // 4000 B
    __shared__ int hist[NBUK], lstart[NBUK], gbase[NBUK];
    const int t = threadIdx.x;
    const int base = blockIdx.x * EPB;
    const int* rows; const int* colsp; const float* valsp; int2* meta; int* cnt;
    if (blockIdx.y == 0) { rows = rA; colsp = cA; valsp = vA; meta = metaA; cnt = cntA; }
    else                 { rows = rB; colsp = cB; valsp = vB; meta = metaB; cnt = cntB; }

    for (int i = t; i < NBUK; i += 256) hist[i] = 0;
    __syncthreads();
    for (int i = t; i < EPB; i += 256)
        atomicAdd(&hist[rows[base + i] >> 7], 1);
    __syncthreads();
    if (t == 0) {
        int s = 0;
        for (int b = 0; b < NBUK; b++) { lstart[b] = s; s += hist[b]; }
    }
    __syncthreads();
    if (t < NBUK) hist[t] = lstart[t];          // reuse hist as cursor
    __syncthreads();
    for (int i = t; i < EPB; i += 256) {
        int r = rows[base + i];
        int c = colsp[base + i];
        float v = valsp[base + i];
        int b = r >> 7;
        int p = atomicAdd(&hist[b], 1);
        stage[p] = make_int2(((r & 127) << 24) | (c * (B_ * 2)),
                             __float_as_int(0.9f * v));
        bkid[p] = (unsigned char)b;
    }
    __syncthreads();
    if (t < NBUK) gbase[t] = atomicAdd(&cnt[t], hist[t] - lstart[t]);
    __syncthreads();
    for (int i = t; i < EPB; i += 256) {
        int b = bkid[i];
        meta[(size_t)b * BCAP + gbase[b] + (i - lstart[b])] = stage[i];
    }
}

// ---------------- pass 2: in-bucket counting sort -> exact CSR -----------
// Also zeroes the 128-entry padding tail (last bucket's block).
__global__ __launch_bounds__(256) void rowsort_kernel(
        const int2* __restrict__ metaA, const int* __restrict__ cntA,
        int2* __restrict__ sortedA, int* __restrict__ rpA,
        const int2* __restrict__ metaB, const int* __restrict__ cntB,
        int2* __restrict__ sortedB, int* __restrict__ rpB) {
    __shared__ int2 stage[BCAP];                // 36864 B
    __shared__ int2 sorted[BCAP];               // 36864 B
    __shared__ int carr[NBUK];
    __shared__ int hist[128], lstart[128];
    const int t = threadIdx.x;
    const int buk = blockIdx.x;
    const int2* meta; const int* cnt; int2* outp; int* rp;
    if (blockIdx.y == 0) { meta = metaA; cnt = cntA; outp = sortedA; rp = rpA; }
    else                 { meta = metaB; cnt = cntB; outp = sortedB; rp = rpB; }

    if (t < NBUK) carr[t] = cnt[t];
    if (t < 128) hist[t] = 0;
    __syncthreads();
    int bukStart = 0, nE = carr[buk];
    for (int b = 0; b < NBUK; b++) bukStart += (b < buk) ? carr[b] : 0;

    const int2* mp = meta + (size_t)buk * BCAP;
    for (int i = t; i < nE; i += 256) {
        int2 m = mp[i];
        stage[i] = m;
        atomicAdd(&hist[(unsigned)m.x >> 24], 1);
    }
    __syncthreads();
    if (t == 0) {
        int s = 0;
        for (int r = 0; r < 128; r++) { lstart[r] = s; s += hist[r]; }
    }
    __syncthreads();
    if (t < 128) hist[t] = lstart[t];           // reuse as cursor
    __syncthreads();
    for (int i = t; i < nE; i += 256) {
        int2 m = stage[i];
        int r = (unsigned)m.x >> 24;
        int p = atomicAdd(&hist[r], 1);
        sorted[p] = make_int2(m.x & 0xFFFFFF, m.y);
    }
    __syncthreads();
    for (int i = t; i < nE; i += 256)
        outp[bukStart + i] = sorted[i];
    if (t < 128) {
        int g = buk * 128 + t;
        if (g < G_) rp[g] = bukStart + lstart[t];
    }
    if (buk == NBUK - 1) {
        if (t == 0) rp[G_] = bukStart + nE;
        if (t < 128) outp[NNZ_ + t] = make_int2(0, 0);  // lockstep overrun pad
    }
}

// ---------------- SPMM f16, 2x128-col chunks, XCD-affine -----------------
// grid 2500*4; combo = bid&3 -> (matrix, chunk). XCD k serves combo k%4,
// gather working set 5.12MB (~L2 + small L3 spill). Half-wave per row,
// each lane 4 cols (8B dwordx2 gather). vals pre-scaled by 0.9.
__global__ __launch_bounds__(256) void spmm_kernel(
        const int* __restrict__ rpA, const int2* __restrict__ metaA,
        const __half* __restrict__ xinA, __half* __restrict__ xoutA,
        const int* __restrict__ rpB, const int2* __restrict__ metaB,
        const __half* __restrict__ xinB, __half* __restrict__ xoutB) {
    const int bid    = blockIdx.x;
    const int combo  = bid & 3;
    const int rowblk = bid >> 2;
    const int chunk  = combo & 1;
    const int t = threadIdx.x;
    const int wave = t >> 6, lane = t & 63;
    const int half = lane >> 5, cl = lane & 31;
    const int g = rowblk * 8 + wave * 2 + half;
    const int loff = chunk * 256 + cl * 8;       // byte offset within x row
    const int* rp; const int2* meta; const __half* xin; __half* xout;
    if (combo < 2) { rp = rpA; meta = metaA; xin = xinA; xout = xoutA; }
    else           { rp = rpB; meta = metaB; xin = xinB; xout = xoutB; }
    int beg = rp[g];
    int n   = rp[g + 1] - beg;
    int nother = __shfl_xor(n, 32);
    int nmax = n > nother ? n : nother;
    const char* xb = (const char*)xin + loff;
    float a0 = 0.f, a1 = 0.f, a2 = 0.f, a3 = 0.f;
    int e = 0;
    for (; e + 4 <= nmax; e += 4) {
        int2 m0 = meta[beg + e],     m1 = meta[beg + e + 1];
        int2 m2 = meta[beg + e + 2], m3 = meta[beg + e + 3];
        float v0 = (e + 0 < n) ? __int_as_float(m0.y) : 0.f;
        float v1 = (e + 1 < n) ? __int_as_float(m1.y) : 0.f;
        float v2 = (e + 2 < n) ? __int_as_float(m2.y) : 0.f;
        float v3 = (e + 3 < n) ? __int_as_float(m3.y) : 0.f;
        uint2 r0 = *(const uint2*)(xb + m0.x);
        uint2 r1 = *(const uint2*)(xb + m1.x);
        uint2 r2 = *(const uint2*)(xb + m2.x);
        uint2 r3 = *(const uint2*)(xb + m3.x);
        float2 l0 = __half22float2(*(__half2*)&r0.x), h0 = __half22float2(*(__half2*)&r0.y);
        float2 l1 = __half22float2(*(__half2*)&r1.x), h1 = __half22float2(*(__half2*)&r1.y);
        float2 l2 = __half22float2(*(__half2*)&r2.x), h2 = __half22float2(*(__half2*)&r2.y);
        float2 l3 = __half22float2(*(__half2*)&r3.x), h3 = __half22float2(*(__half2*)&r3.y);
        a0 = fmaf(v0, l0.x, a0); a1 = fmaf(v0, l0.y, a1);
        a2 = fmaf(v0, h0.x, a2); a3 = fmaf(v0, h0.y, a3);
        a0 = fmaf(v1, l1.x, a0); a1 = fmaf(v1, l1.y, a1);
        a2 = fmaf(v1, h1.x, a2); a3 = fmaf(v1, h1.y, a3);
        a0 = fmaf(v2, l2.x, a0); a1 = fmaf(v2, l2.y, a1);
        a2 = fmaf(v2, h2.x, a2); a3 = fmaf(v2, h2.y, a3);
        a0 = fmaf(v3, l3.x, a0); a1 = fmaf(v3, l3.y, a1);
        a2 = fmaf(v3, h3.x, a2); a3 = fmaf(v3, h3.y, a3);
    }
    for (; e < nmax; ++e) {
        int2 m = meta[beg + e];
        float v = (e < n) ? __int_as_float(m.y) : 0.f;
        uint2 r = *(const uint2*)(xb + m.x);
        float2 l = __half22float2(*(__half2*)&r.x), h = __half22float2(*(__half2*)&r.y);
        a0 = fmaf(v, l.x, a0); a1 = fmaf(v, l.y, a1);
        a2 = fmaf(v, h.x, a2); a3 = fmaf(v, h.y, a3);
    }
    __half2 o0 = __floats2half2_rn(a0, a1);
    __half2 o1 = __floats2half2_rn(a2, a3);
    uint2 ov;
    ov.x = *(unsigned*)&o0;
    ov.y = *(unsigned*)&o1;
    *(uint2*)((char*)xout + (size_t)g * (B_ * 2) + loff) = ov;
}

// ---------------- combine + transpose + f16: -> had[b][g] ----------------
__global__ __launch_bounds__(256) void combine_kernel(
        const __half* __restrict__ X2s, const __half* __restrict__ X0s,
        const __half* __restrict__ X2t, const __half* __restrict__ X0t,
        __half* __restrict__ hadBK) {
    __shared__ float lds[64][65];       // [g][b]
    const int t = threadIdx.x;
    const int gb = blockIdx.x * 64, bb = blockIdx.y * 64;
    const int cl = t & 31, row0 = t >> 5;
#pragma unroll
    for (int r = 0; r < 8; r++) {
        int gl = row0 + r * 8;
        int g = gb + gl;
        float px = 0.f, py = 0.f;
        if (g < G_) {
            size_t idx = (size_t)g * B_ + bb + cl * 2;
            float2 x2s = __half22float2(*(const __half2*)(X2s + idx));
            float2 x0s = __half22float2(*(const __half2*)(X0s + idx));
            float2 x2t = __half22float2(*(const __half2*)(X2t + idx));
            float2 x0t = __half22float2(*(const __half2*)(X0t + idx));
            px = (x2s.x + 0.1f * x0s.x) * (x2t.x + 0.1f * x0t.x);
            py = (x2s.y + 0.1f * x0s.y) * (x2t.y + 0.1f * x0t.y);
        }
        lds[gl][cl * 2]     = px;
        lds[gl][cl * 2 + 1] = py;
    }
    __syncthreads();
#pragma unroll
    for (int r = 0; r < 8; r++) {
        int bl = row0 + r * 8;
        int g0 = gb + cl * 2;
        if (g0 < G_) {
            __half2 hv = __floats2half2_rn(lds[cl * 2][bl], lds[cl * 2 + 1][bl]);
            *(__half2*)(hadBK + (size_t)(bb + bl) * G_ + g0) = hv;
        }
    }
}

// ---------------- GEMM1 MFMA f16 with register prefetch ------------------
// tile 256(b) x 128(o) x BK32, 512 thr = 8 waves. Next step's global loads
// issue between barriers so HBM latency hides under MFMA (1 block/CU).
__global__ __launch_bounds__(512) void gemm1_kernel(
        const __half* __restrict__ hadBK, const float* __restrict__ W1,
        float* __restrict__ part) {
    __shared__ _Float16 a_lds[256][40];   // stride 80B = 16B-aligned, 2-way banks
    __shared__ _Float16 b_lds[128][40];
    const int t = threadIdx.x;
    const int lane = t & 63, wid = t >> 6;
    const int wm = wid >> 1, wn = wid & 1;
    const int l15 = lane & 15, l4 = lane >> 4;
    const int ob = blockIdx.x * 128;
    const int kb = blockIdx.y * KCH_;
    int kend = kb + KCH_; if (kend > G_) kend = G_;
    const int nsteps = (kend - kb) >> 5;       // 20, or 5 at z=31
    const int ar = t >> 1, ah = t & 1;
    const int br = t >> 2, bs = t & 3;
    const _Float16* hadH = (const _Float16*)hadBK;
    const _Float16* asrc = hadH + (size_t)ar * G_ + ah * 16;
    const float*    bsrc = W1 + (size_t)(ob + br) * G_ + bs * 8;
    f4 acc[4][4] = {};
    // prologue: load step 0 into regs
    h8 ra0 = *(const h8*)(asrc + kb);
    h8 ra1 = *(const h8*)(asrc + kb + 8);
    f4 rb0 = *(const f4*)(bsrc + kb);
    f4 rb1 = *(const f4*)(bsrc + kb + 4);
    for (int s = 0; s < nsteps; ++s) {
        // write current regs to LDS
        *(h8*)&a_lds[ar][ah * 16]     = ra0;
        *(h8*)&a_lds[ar][ah * 16 + 8] = ra1;
        {
            h8 h;
            h[0] = (_Float16)rb0[0]; h[1] = (_Float16)rb0[1];
            h[2] = (_Float16)rb0[2]; h[3] = (_Float16)rb0[3];
            h[4] = (_Float16)rb1[0]; h[5] = (_Float16)rb1[1];
            h[6] = (_Float16)rb1[2]; h[7] = (_Float16)rb1[3];
            *(h8*)&b_lds[br][bs * 8] = h;
        }
        __syncthreads();
        // issue next step's global loads (overlap with MFMA below)
        if (s + 1 < nsteps) {
            const int k1 = kb + (s + 1) * 32;
            ra0 = *(const h8*)(asrc + k1);
            ra1 = *(const h8*)(asrc + k1 + 8);
            rb0 = *(const f4*)(bsrc + k1);
            rb1 = *(const f4*)(bsrc + k1 + 4);
        }
        h8 af[4], bf[4];
#pragma unroll
        for (int m = 0; m < 4; m++)
            af[m] = *(const h8*)&a_lds[wm * 64 + m * 16 + l15][l4 * 8];
#pragma unroll
        for (int n = 0; n < 4; n++)
            bf[n] = *(const h8*)&b_lds[wn * 64 + n * 16 + l15][l4 * 8];
#pragma unroll
        for (int m = 0; m < 4; m++)
#pragma unroll
            for (int n = 0; n < 4; n++)
                acc[m][n] = __builtin_amdgcn_mfma_f32_16x16x32_f16(
                    af[m], bf[n], acc[m][n], 0, 0, 0);
        __syncthreads();
    }
    const size_t zoff = (size_t)blockIdx.y * (B_ * 1024);
#pragma unroll
    for (int m = 0; m < 4; m++)
#pragma unroll
        for (int n = 0; n < 4; n++)
#pragma unroll
            for (int j = 0; j < 4; j++) {
                int b = wm * 64 + m * 16 + l4 * 4 + j;
                int o = ob + wn * 64 + n * 16 + l15;
                part[zoff + (size_t)b * 1024 + o] = acc[m][n][j];
            }
}

// ---------------- reduce split-K + bias + relu -> h1 ---------------------
__global__ __launch_bounds__(256) void reduce_kernel(
        const float* __restrict__ part, const float* __restrict__ b1,
        float* __restrict__ h1) {
    int i = blockIdx.x * 256 + threadIdx.x;    // 262144 total
    float s = 0.f;
#pragma unroll
    for (int z = 0; z < NZ_; z++) s += part[(size_t)z * 262144 + i];
    h1[i] = fmaxf(s + b1[i & 1023], 0.f);
}

// ---------------- fused GEMM2 (relu) + GEMM3 -----------------------------
__global__ __launch_bounds__(128) void gemm23_kernel(
        const float* __restrict__ h1, const float* __restrict__ W2,
        const float* __restrict__ b2, const float* __restrict__ W3,
        const float* __restrict__ b3, float* __restrict__ out) {
    __shared__ float h1row[1024];
    __shared__ float h2[128];
    const int b = blockIdx.x, t = threadIdx.x;
    *(f4*)&h1row[t * 4]       = *(const f4*)(h1 + (size_t)b * 1024 + t * 4);
    *(f4*)&h1row[512 + t * 4] = *(const f4*)(h1 + (size_t)b * 1024 + 512 + t * 4);
    __syncthreads();
    {
        float acc = b2[t];
        const f4* w  = (const f4*)(W2 + (size_t)t * 1024);
        const f4* hr = (const f4*)h1row;
        for (int k = 0; k < 256; k++) {
            f4 wv = w[k], hv = hr[k];
            acc += wv[0] * hv[0] + wv[1] * hv[1] + wv[2] * hv[2] + wv[3] * hv[3];
        }
        h2[t] = fmaxf(acc, 0.f);
    }
    __syncthreads();
    if (t < 33) {
        float acc = b3[t];
        const f4* w  = (const f4*)(W3 + (size_t)t * 128);
        const f4* hv = (const f4*)h2;
#pragma unroll
        for (int k = 0; k < 32; k++) {
            f4 a = w[k], x = hv[k];
            acc += a[0] * x[0] + a[1] * x[1] + a[2] * x[2] + a[3] * x[3];
        }
        out[b * 33 + t] = acc;
    }
}

extern "C" void kernel_launch(void* const* d_in, const int* in_sizes, int n_in,
                              void* d_out, int out_size, void* d_ws, size_t ws_size,
                              hipStream_t stream) {
    const float* x_sample  = (const float*)d_in[0];
    const float* x_TF      = (const float*)d_in[1];
    const int*   adj_rows  = (const int*)d_in[2];
    const int*   adj_cols  = (const int*)d_in[3];
    const float* adj_vals  = (const float*)d_in[4];
    const int*   adjT_rows = (const int*)d_in[5];
    const int*   adjT_cols = (const int*)d_in[6];
    const float* adjT_vals = (const float*)d_in[7];
    const float* emb_mut   = (const float*)d_in[8];
    const float* bias_mut  = (const float*)d_in[9];
    const float* emb_exp   = (const float*)d_in[10];
    const float* bias_exp  = (const float*)d_in[11];
    const float* W1 = (const float*)d_in[12];
    const float* b1 = (const float*)d_in[13];
    const float* W2 = (const float*)d_in[14];
    const float* b2 = (const float*)d_in[15];
    const float* W3 = (const float*)d_in[16];
    const float* b3 = (const float*)d_in[17];
    float* out = (float*)d_out;

    // ---- workspace layout (~120 MB) ----
    char* w = (char*)d_ws;
    auto alloc = [&](size_t bytes) {
        char* p = w; w += (bytes + 255) & ~(size_t)255; return p;
    };
    __half* X0s = (__half*)alloc(5120000 * 2);
    __half* X1s = (__half*)alloc(5120000 * 2);
    __half* X2s = (__half*)alloc(5120000 * 2);
    __half* X0t = (__half*)alloc(5120000 * 2);
    __half* X1t = (__half*)alloc(5120000 * 2);
    __half* X2t = (__half*)alloc(5120000 * 2);
    float*  part = (float*)alloc((size_t)NZ_ * 262144 * 4);   // 33.5 MB
    float*  h1   = (float*)alloc(262144 * 4);
    int2*   metaA   = (int2*)alloc((size_t)NBUK * BCAP * 8);  // 5.79 MB bucketed
    int2*   metaB   = (int2*)alloc((size_t)NBUK * BCAP * 8);
    int2*   sortedA = (int2*)alloc((size_t)(NNZ_ + 128) * 8); // 5.12 MB CSR-sorted
    int2*   sortedB = (int2*)alloc((size_t)(NNZ_ + 128) * 8);
    int*    cnt   = (int*)alloc(2 * NBUK * 4);
    int*    cntA  = cnt;
    int*    cntB  = cnt + NBUK;
    int*    rpA   = (int*)alloc(20001 * 4);
    int*    rpB   = (int*)alloc(20001 * 4);
    __half* hadBK = X1s;    // overlay: X1s dead after spmm iter 2

    zero_kernel<<<2, 256, 0, stream>>>((unsigned int*)cnt, 2 * NBUK);

    embed_kernel<<<dim3(313, 4), 256, 0, stream>>>(
        x_sample, x_TF, emb_mut, bias_mut, emb_exp, bias_exp, X0s, X0t);

    // two-pass coalesced CSR build (pad tail written by rowsort)
    binsort_kernel<<<dim3(160, 2), 256, 0, stream>>>(
        adj_rows, adj_cols, adj_vals, adjT_rows, adjT_cols, adjT_vals,
        metaA, cntA, metaB, cntB);
    rowsort_kernel<<<dim3(NBUK, 2), 256, 0, stream>>>(
        metaA, cntA, sortedA, rpA, metaB, cntB, sortedB, rpB);

    // K = 2 PPR iterations (0.9 folded into vals), 2x128-col chunks
    spmm_kernel<<<10000, 256, 0, stream>>>(rpA, sortedA, X0s, X1s,
                                           rpB, sortedB, X0t, X1t);
    spmm_kernel<<<10000, 256, 0, stream>>>(rpA, sortedA, X1s, X2s,
                                           rpB, sortedB, X1t, X2t);

    combine_kernel<<<dim3(313, 4), 256, 0, stream>>>(X2s, X0s, X2t, X0t, hadBK);

    gemm1_kernel<<<dim3(8, NZ_), 512, 0, stream>>>(hadBK, W1, part);
    reduce_kernel<<<1024, 256, 0, stream>>>(part, b1, h1);
    gemm23_kernel<<<B_, 128, 0, stream>>>(h1, W2, b2, W3, b3, out);
}

// Round 7
// 436.266 us; speedup vs baseline: 8.3878x; 1.0218x over previous
//
#include <hip/hip_runtime.h>
#include <hip/hip_fp16.h>

#define G_   20000
#define B_   256
#define NNZ_ 640000
#define KCH_ 640       // gemm1 split-K chunk (20 steps of 32; z=31 does 5)
#define NZ_  32        // split-K factor
#define NBUK 157       // ceil(20000/128) row buckets of 128 rows
#define BCAP 4608      // per-bucket segment capacity (avg 4076, >8 sigma slack)
#define EPB  4000      // binsort entries per block (160 blocks x 4000 = NNZ)

typedef float f4 __attribute__((ext_vector_type(4)));
typedef _Float16 h8 __attribute__((ext_vector_type(8)));

// ---------------- zero scratch ------------------------------------------
__global__ __launch_bounds__(256) void zero_kernel(unsigned int* p, int n) {
    int i = blockIdx.x * 256 + threadIdx.x;
    if (i < n) p[i] = 0u;
}

// ---------------- embed + transpose: [B,G] f32 -> [G,B] f16 --------------
__global__ __launch_bounds__(256) void embed_kernel(
        const float* __restrict__ xsamp, const float* __restrict__ xtf,
        const float* __restrict__ em, const float* __restrict__ bm,
        const float* __restrict__ ee, const float* __restrict__ be,
        __half* __restrict__ X0s, __half* __restrict__ X0t) {
    __shared__ float lds[64][65];       // [b][g]
    const int t  = threadIdx.x;
    const int gb = blockIdx.x * 64, bb = blockIdx.y * 64;
    const float a_m = em[0], c_m = bm[0], a_e = ee[0], c_e = be[0];
    const int gl = t & 63, brow0 = t >> 6;     // load mapping
    const int cl = t & 31, row0  = t >> 5;     // store mapping
    const int g_l = gb + gl;
#pragma unroll
    for (int r = 0; r < 16; r++) {
        int bl = brow0 + r * 4;
        float v = 0.f;
        if (g_l < G_) v = xsamp[(size_t)(bb + bl) * G_ + g_l];
        lds[bl][gl] = fmaxf(a_m * v + c_m, 0.f);
    }
    __syncthreads();
#pragma unroll
    for (int r = 0; r < 8; r++) {
        int gl2 = row0 + r * 8;
        int g = gb + gl2;
        if (g < G_) {
            __half2 hv = __floats2half2_rn(lds[cl * 2][gl2], lds[cl * 2 + 1][gl2]);
            *(__half2*)(X0s + (size_t)g * B_ + bb + cl * 2) = hv;
        }
    }
    __syncthreads();
#pragma unroll
    for (int r = 0; r < 16; r++) {
        int bl = brow0 + r * 4;
        float v = 0.f;
        if (g_l < G_) v = xtf[(size_t)(bb + bl) * G_ + g_l];
        lds[bl][gl] = fmaxf(a_e * v + c_e, 0.f);
    }
    __syncthreads();
#pragma unroll
    for (int r = 0; r < 8; r++) {
        int gl2 = row0 + r * 8;
        int g = gb + gl2;
        if (g < G_) {
            __half2 hv = __floats2half2_rn(lds[cl * 2][gl2], lds[cl * 2 + 1][gl2]);
            *(__half2*)(X0t + (size_t)g * B_ + bb + cl * 2) = hv;
        }
    }
}

// ---------------- pass 1: bucket sort COO into 128-row bins --------------
// meta.x = (rowInBucket<<24) | col*512 ; meta.y = f32 bits of 0.9*val.
__global__ __launch_bounds__(256) void binsort_kernel(
        const int* __restrict__ rA, const int* __restrict__ cA, const float* __restrict__ vA,
        const int* __restrict__ rB, const int* __restrict__ cB, const float* __restrict__ vB,
        int2* __restrict__ metaA, int* __restrict__ cntA,
        int2* __restrict__ metaB, int* __restrict__ cntB) {
    __shared__ int2 stage[EPB];                 // 32000 B
    __shared__ unsigned char bkid[EPB];         // 4000 B
    __shared__ int hist[NBUK], lstart[NBUK], gbase[NBUK];
    const int t = threadIdx.x;
    const int base = blockIdx.x * EPB;
    const int* rows; const int* colsp; const float* valsp; int2* meta; int* cnt;
    if (blockIdx.y == 0) { rows = rA; colsp = cA; valsp = vA; meta = metaA; cnt = cntA; }
    else                 { rows = rB; colsp = cB; valsp = vB; meta = metaB; cnt = cntB; }

    for (int i = t; i < NBUK; i += 256) hist[i] = 0;
    __syncthreads();
    for (int i = t; i < EPB; i += 256)
        atomicAdd(&hist[rows[base + i] >> 7], 1);
    __syncthreads();
    if (t == 0) {
        int s = 0;
        for (int b = 0; b < NBUK; b++) { lstart[b] = s; s += hist[b]; }
    }
    __syncthreads();
    if (t < NBUK) hist[t] = lstart[t];          // reuse hist as cursor
    __syncthreads();
    for (int i = t; i < EPB; i += 256) {
        int r = rows[base + i];
        int c = colsp[base + i];
        float v = valsp[base + i];
        int b = r >> 7;
        int p = atomicAdd(&hist[b], 1);
        stage[p] = make_int2(((r & 127) << 24) | (c * (B_ * 2)),
                             __float_as_int(0.9f * v));
        bkid[p] = (unsigned char)b;
    }
    __syncthreads();
    if (t < NBUK) gbase[t] = atomicAdd(&cnt[t], hist[t] - lstart[t]);
    __syncthreads();
    for (int i = t; i < EPB; i += 256) {
        int b = bkid[i];
        meta[(size_t)b * BCAP + gbase[b] + (i - lstart[b])] = stage[i];
    }
}

// ---------------- pass 2: composite-key counting sort -> CSR -------------
// key = rowInBucket*16 | colbucket (col>>11): entries grouped by row, and
// WITHIN each row by ascending 2048-col windows -> monotone x access in
// spmm (L2-resident moving window). One block per (bucket, matrix).
__global__ __launch_bounds__(256) void rowsort_kernel(
        const int2* __restrict__ metaA, const int* __restrict__ cntA,
        int2* __restrict__ sortedA, int* __restrict__ rpA,
        const int2* __restrict__ metaB, const int* __restrict__ cntB,
        int2* __restrict__ sortedB, int* __restrict__ rpB) {
    __shared__ int2 stage[BCAP];                // 36864 B
    __shared__ int2 sorted[BCAP];               // 36864 B
    __shared__ int hist[2048];                  // 8192 B (counts->starts->cursors)
    __shared__ int scanbuf[256];
    __shared__ int rowstart[128];
    __shared__ int carr[NBUK];
    const int t = threadIdx.x;
    const int buk = blockIdx.x;
    const int2* meta; const int* cnt; int2* outp; int* rp;
    if (blockIdx.y == 0) { meta = metaA; cnt = cntA; outp = sortedA; rp = rpA; }
    else                 { meta = metaB; cnt = cntB; outp = sortedB; rp = rpB; }

    if (t < NBUK) carr[t] = cnt[t];
    for (int i = t; i < 2048; i += 256) hist[i] = 0;
    __syncthreads();
    int bukStart = 0;
    const int nE = carr[buk];
    for (int b = 0; b < buk; b++) bukStart += carr[b];

    const int2* mp = meta + (size_t)buk * BCAP;
    for (int i = t; i < nE; i += 256) {
        int2 m = mp[i];
        stage[i] = m;
        unsigned ux = (unsigned)m.x;
        int key = ((ux >> 24) << 4) | ((ux & 0xFFFFFF) >> 20);  // row*16 | c>>11
        atomicAdd(&hist[key], 1);
    }
    __syncthreads();
    // parallel exclusive scan over 2048 keys (256 thr x 8)
    int loc[8];
    {
        int s = 0;
#pragma unroll
        for (int i = 0; i < 8; i++) { loc[i] = s; s += hist[t * 8 + i]; }
        scanbuf[t] = s;
    }
    __syncthreads();
    for (int off = 1; off < 256; off <<= 1) {
        int v = scanbuf[t];
        int add = (t >= off) ? scanbuf[t - off] : 0;
        __syncthreads();
        scanbuf[t] = v + add;
        __syncthreads();
    }
    {
        int pre = (t == 0) ? 0 : scanbuf[t - 1];
#pragma unroll
        for (int i = 0; i < 8; i++) hist[t * 8 + i] = pre + loc[i];
    }
    __syncthreads();
    if (t < 128) rowstart[t] = hist[t << 4];    // row start before cursor bump
    __syncthreads();
    for (int i = t; i < nE; i += 256) {
        int2 m = stage[i];
        unsigned ux = (unsigned)m.x;
        int key = ((ux >> 24) << 4) | ((ux & 0xFFFFFF) >> 20);
        int p = atomicAdd(&hist[key], 1);
        sorted[p] = make_int2(m.x & 0xFFFFFF, m.y);
    }
    __syncthreads();
    for (int i = t; i < nE; i += 256)
        outp[bukStart + i] = sorted[i];
    if (t < 128) {
        int g = buk * 128 + t;
        if (g < G_) rp[g] = bukStart + rowstart[t];
    }
    if (buk == NBUK - 1 && t == 0) rp[G_] = bukStart + nE;
}

// ---------------- SPMM f16, full row per wave, col-sorted entries --------
// grid 5000*2; combo = bid&1 -> matrix (XCDs 0/2/4/6 -> A, 1/3/5/7 -> B).
// Wave owns row g: 64 lanes x 8B = full 256-col row; n is wave-uniform
// (no predication). Entries ascend in column -> monotone gather window.
__global__ __launch_bounds__(256) void spmm_kernel(
        const int* __restrict__ rpA, const int2* __restrict__ metaA,
        const __half* __restrict__ xinA, __half* __restrict__ xoutA,
        const int* __restrict__ rpB, const int2* __restrict__ metaB,
        const __half* __restrict__ xinB, __half* __restrict__ xoutB) {
    const int bid   = blockIdx.x;
    const int combo = bid & 1;
    const int t = threadIdx.x;
    const int wave = t >> 6, lane = t & 63;
    const int g = (bid >> 1) * 4 + wave;
    const int* rp; const int2* meta; const __half* xin; __half* xout;
    if (combo == 0) { rp = rpA; meta = metaA; xin = xinA; xout = xoutA; }
    else            { rp = rpB; meta = metaB; xin = xinB; xout = xoutB; }
    const int beg = rp[g];
    const int n   = rp[g + 1] - beg;
    const char* xb = (const char*)xin + lane * 8;
    float a0 = 0.f, a1 = 0.f, a2 = 0.f, a3 = 0.f;
    int e = 0;
    for (; e + 4 <= n; e += 4) {
        int2 m0 = meta[beg + e],     m1 = meta[beg + e + 1];
        int2 m2 = meta[beg + e + 2], m3 = meta[beg + e + 3];
        float v0 = __int_as_float(m0.y);
        float v1 = __int_as_float(m1.y);
        float v2 = __int_as_float(m2.y);
        float v3 = __int_as_float(m3.y);
        uint2 r0 = *(const uint2*)(xb + m0.x);
        uint2 r1 = *(const uint2*)(xb + m1.x);
        uint2 r2 = *(const uint2*)(xb + m2.x);
        uint2 r3 = *(const uint2*)(xb + m3.x);
        float2 l0 = __half22float2(*(__half2*)&r0.x), h0 = __half22float2(*(__half2*)&r0.y);
        float2 l1 = __half22float2(*(__half2*)&r1.x), h1 = __half22float2(*(__half2*)&r1.y);
        float2 l2 = __half22float2(*(__half2*)&r2.x), h2 = __half22float2(*(__half2*)&r2.y);
        float2 l3 = __half22float2(*(__half2*)&r3.x), h3 = __half22float2(*(__half2*)&r3.y);
        a0 = fmaf(v0, l0.x, a0); a1 = fmaf(v0, l0.y, a1);
        a2 = fmaf(v0, h0.x, a2); a3 = fmaf(v0, h0.y, a3);
        a0 = fmaf(v1, l1.x, a0); a1 = fmaf(v1, l1.y, a1);
        a2 = fmaf(v1, h1.x, a2); a3 = fmaf(v1, h1.y, a3);
        a0 = fmaf(v2, l2.x, a0); a1 = fmaf(v2, l2.y, a1);
        a2 = fmaf(v2, h2.x, a2); a3 = fmaf(v2, h2.y, a3);
        a0 = fmaf(v3, l3.x, a0); a1 = fmaf(v3, l3.y, a1);
        a2 = fmaf(v3, h3.x, a2); a3 = fmaf(v3, h3.y, a3);
    }
    for (; e < n; ++e) {
        int2 m = meta[beg + e];
        float v = __int_as_float(m.y);
        uint2 r = *(const uint2*)(xb + m.x);
        float2 l = __half22float2(*(__half2*)&r.x), h = __half22float2(*(__half2*)&r.y);
        a0 = fmaf(v, l.x, a0); a1 = fmaf(v, l.y, a1);
        a2 = fmaf(v, h.x, a2); a3 = fmaf(v, h.y, a3);
    }
    __half2 o0 = __floats2half2_rn(a0, a1);
    __half2 o1 = __floats2half2_rn(a2, a3);
    uint2 ov;
    ov.x = *(unsigned*)&o0;
    ov.y = *(unsigned*)&o1;
    *(uint2*)((char*)xout + (size_t)g * (B_ * 2) + lane * 8) = ov;
}

// ---------------- combine + transpose + f16: -> had[b][g] ----------------
__global__ __launch_bounds__(256) void combine_kernel(
        const __half* __restrict__ X2s, const __half* __restrict__ X0s,
        const __half* __restrict__ X2t, const __half* __restrict__ X0t,
        __half* __restrict__ hadBK) {
    __shared__ float lds[64][65];       // [g][b]
    const int t = threadIdx.x;
    const int gb = blockIdx.x * 64, bb = blockIdx.y * 64;
    const int cl = t & 31, row0 = t >> 5;
#pragma unroll
    for (int r = 0; r < 8; r++) {
        int gl = row0 + r * 8;
        int g = gb + gl;
        float px = 0.f, py = 0.f;
        if (g < G_) {
            size_t idx = (size_t)g * B_ + bb + cl * 2;
            float2 x2s = __half22float2(*(const __half2*)(X2s + idx));
            float2 x0s = __half22float2(*(const __half2*)(X0s + idx));
            float2 x2t = __half22float2(*(const __half2*)(X2t + idx));
            float2 x0t = __half22float2(*(const __half2*)(X0t + idx));
            px = (x2s.x + 0.1f * x0s.x) * (x2t.x + 0.1f * x0t.x);
            py = (x2s.y + 0.1f * x0s.y) * (x2t.y + 0.1f * x0t.y);
        }
        lds[gl][cl * 2]     = px;
        lds[gl][cl * 2 + 1] = py;
    }
    __syncthreads();
#pragma unroll
    for (int r = 0; r < 8; r++) {
        int bl = row0 + r * 8;
        int g0 = gb + cl * 2;
        if (g0 < G_) {
            __half2 hv = __floats2half2_rn(lds[cl * 2][bl], lds[cl * 2 + 1][bl]);
            *(__half2*)(hadBK + (size_t)(bb + bl) * G_ + g0) = hv;
        }
    }
}

// ---------------- GEMM1 MFMA f16 with register prefetch ------------------
__global__ __launch_bounds__(512) void gemm1_kernel(
        const __half* __restrict__ hadBK, const float* __restrict__ W1,
        float* __restrict__ part) {
    __shared__ _Float16 a_lds[256][40];   // stride 80B = 16B-aligned, 2-way banks
    __shared__ _Float16 b_lds[128][40];
    const int t = threadIdx.x;
    const int lane = t & 63, wid = t >> 6;
    const int wm = wid >> 1, wn = wid & 1;
    const int l15 = lane & 15, l4 = lane >> 4;
    const int ob = blockIdx.x * 128;
    const int kb = blockIdx.y * KCH_;
    int kend = kb + KCH_; if (kend > G_) kend = G_;
    const int nsteps = (kend - kb) >> 5;       // 20, or 5 at z=31
    const int ar = t >> 1, ah = t & 1;
    const int br = t >> 2, bs = t & 3;
    const _Float16* hadH = (const _Float16*)hadBK;
    const _Float16* asrc = hadH + (size_t)ar * G_ + ah * 16;
    const float*    bsrc = W1 + (size_t)(ob + br) * G_ + bs * 8;
    f4 acc[4][4] = {};
    h8 ra0 = *(const h8*)(asrc + kb);
    h8 ra1 = *(const h8*)(asrc + kb + 8);
    f4 rb0 = *(const f4*)(bsrc + kb);
    f4 rb1 = *(const f4*)(bsrc + kb + 4);
    for (int s = 0; s < nsteps; ++s) {
        *(h8*)&a_lds[ar][ah * 16]     = ra0;
        *(h8*)&a_lds[ar][ah * 16 + 8] = ra1;
        {
            h8 h;
            h[0] = (_Float16)rb0[0]; h[1] = (_Float16)rb0[1];
            h[2] = (_Float16)rb0[2]; h[3] = (_Float16)rb0[3];
            h[4] = (_Float16)rb1[0]; h[5] = (_Float16)rb1[1];
            h[6] = (_Float16)rb1[2]; h[7] = (_Float16)rb1[3];
            *(h8*)&b_lds[br][bs * 8] = h;
        }
        __syncthreads();
        if (s + 1 < nsteps) {
            const int k1 = kb + (s + 1) * 32;
            ra0 = *(const h8*)(asrc + k1);
            ra1 = *(const h8*)(asrc + k1 + 8);
            rb0 = *(const f4*)(bsrc + k1);
            rb1 = *(const f4*)(bsrc + k1 + 4);
        }
        h8 af[4], bf[4];
#pragma unroll
        for (int m = 0; m < 4; m++)
            af[m] = *(const h8*)&a_lds[wm * 64 + m * 16 + l15][l4 * 8];
#pragma unroll
        for (int n = 0; n < 4; n++)
            bf[n] = *(const h8*)&b_lds[wn * 64 + n * 16 + l15][l4 * 8];
#pragma unroll
        for (int m = 0; m < 4; m++)
#pragma unroll
            for (int n = 0; n < 4; n++)
                acc[m][n] = __builtin_amdgcn_mfma_f32_16x16x32_f16(
                    af[m], bf[n], acc[m][n], 0, 0, 0);
        __syncthreads();
    }
    const size_t zoff = (size_t)blockIdx.y * (B_ * 1024);
#pragma unroll
    for (int m = 0; m < 4; m++)
#pragma unroll
        for (int n = 0; n < 4; n++)
#pragma unroll
            for (int j = 0; j < 4; j++) {
                int b = wm * 64 + m * 16 + l4 * 4 + j;
                int o = ob + wn * 64 + n * 16 + l15;
                part[zoff + (size_t)b * 1024 + o] = acc[m][n][j];
            }
}

// ---------------- reduce split-K + bias + relu -> h1 ---------------------
__global__ __launch_bounds__(256) void reduce_kernel(
        const float* __restrict__ part, const float* __restrict__ b1,
        float* __restrict__ h1) {
    int i = blockIdx.x * 256 + threadIdx.x;    // 262144 total
    float s = 0.f;
#pragma unroll
    for (int z = 0; z < NZ_; z++) s += part[(size_t)z * 262144 + i];
    h1[i] = fmaxf(s + b1[i & 1023], 0.f);
}

// ---------------- fused GEMM2 (relu) + GEMM3 -----------------------------
__global__ __launch_bounds__(128) void gemm23_kernel(
        const float* __restrict__ h1, const float* __restrict__ W2,
        const float* __restrict__ b2, const float* __restrict__ W3,
        const float* __restrict__ b3, float* __restrict__ out) {
    __shared__ float h1row[1024];
    __shared__ float h2[128];
    const int b = blockIdx.x, t = threadIdx.x;
    *(f4*)&h1row[t * 4]       = *(const f4*)(h1 + (size_t)b * 1024 + t * 4);
    *(f4*)&h1row[512 + t * 4] = *(const f4*)(h1 + (size_t)b * 1024 + 512 + t * 4);
    __syncthreads();
    {
        float acc = b2[t];
        const f4* w  = (const f4*)(W2 + (size_t)t * 1024);
        const f4* hr = (const f4*)h1row;
        for (int k = 0; k < 256; k++) {
            f4 wv = w[k], hv = hr[k];
            acc += wv[0] * hv[0] + wv[1] * hv[1] + wv[2] * hv[2] + wv[3] * hv[3];
        }
        h2[t] = fmaxf(acc, 0.f);
    }
    __syncthreads();
    if (t < 33) {
        float acc = b3[t];
        const f4* w  = (const f4*)(W3 + (size_t)t * 128);
        const f4* hv = (const f4*)h2;
#pragma unroll
        for (int k = 0; k < 32; k++) {
            f4 a = w[k], x = hv[k];
            acc += a[0] * x[0] + a[1] * x[1] + a[2] * x[2] + a[3] * x[3];
        }
        out[b * 33 + t] = acc;
    }
}

extern "C" void kernel_launch(void* const* d_in, const int* in_sizes, int n_in,
                              void* d_out, int out_size, void* d_ws, size_t ws_size,
                              hipStream_t stream) {
    const float* x_sample  = (const float*)d_in[0];
    const float* x_TF      = (const float*)d_in[1];
    const int*   adj_rows  = (const int*)d_in[2];
    const int*   adj_cols  = (const int*)d_in[3];
    const float* adj_vals  = (const float*)d_in[4];
    const int*   adjT_rows = (const int*)d_in[5];
    const int*   adjT_cols = (const int*)d_in[6];
    const float* adjT_vals = (const float*)d_in[7];
    const float* emb_mut   = (const float*)d_in[8];
    const float* bias_mut  = (const float*)d_in[9];
    const float* emb_exp   = (const float*)d_in[10];
    const float* bias_exp  = (const float*)d_in[11];
    const float* W1 = (const float*)d_in[12];
    const float* b1 = (const float*)d_in[13];
    const float* W2 = (const float*)d_in[14];
    const float* b2 = (const float*)d_in[15];
    const float* W3 = (const float*)d_in[16];
    const float* b3 = (const float*)d_in[17];
    float* out = (float*)d_out;

    // ---- workspace layout (~120 MB) ----
    char* w = (char*)d_ws;
    auto alloc = [&](size_t bytes) {
        char* p = w; w += (bytes + 255) & ~(size_t)255; return p;
    };
    __half* X0s = (__half*)alloc(5120000 * 2);
    __half* X1s = (__half*)alloc(5120000 * 2);
    __half* X2s = (__half*)alloc(5120000 * 2);
    __half* X0t = (__half*)alloc(5120000 * 2);
    __half* X1t = (__half*)alloc(5120000 * 2);
    __half* X2t = (__half*)alloc(5120000 * 2);
    float*  part = (float*)alloc((size_t)NZ_ * 262144 * 4);   // 33.5 MB
    float*  h1   = (float*)alloc(262144 * 4);
    int2*   metaA   = (int2*)alloc((size_t)NBUK * BCAP * 8);  // 5.79 MB bucketed
    int2*   metaB   = (int2*)alloc((size_t)NBUK * BCAP * 8);
    int2*   sortedA = (int2*)alloc((size_t)(NNZ_ + 128) * 8); // 5.12 MB CSR-sorted
    int2*   sortedB = (int2*)alloc((size_t)(NNZ_ + 128) * 8);
    int*    cnt   = (int*)alloc(2 * NBUK * 4);
    int*    cntA  = cnt;
    int*    cntB  = cnt + NBUK;
    int*    rpA   = (int*)alloc(20001 * 4);
    int*    rpB   = (int*)alloc(20001 * 4);
    __half* hadBK = X1s;    // overlay: X1s dead after spmm iter 2

    zero_kernel<<<2, 256, 0, stream>>>((unsigned int*)cnt, 2 * NBUK);

    embed_kernel<<<dim3(313, 4), 256, 0, stream>>>(
        x_sample, x_TF, emb_mut, bias_mut, emb_exp, bias_exp, X0s, X0t);

    // two-pass coalesced CSR build (row-grouped, col-sorted within row)
    binsort_kernel<<<dim3(160, 2), 256, 0, stream>>>(
        adj_rows, adj_cols, adj_vals, adjT_rows, adjT_cols, adjT_vals,
        metaA, cntA, metaB, cntB);
    rowsort_kernel<<<dim3(NBUK, 2), 256, 0, stream>>>(
        metaA, cntA, sortedA, rpA, metaB, cntB, sortedB, rpB);

    // K = 2 PPR iterations (0.9 folded into vals), full-row waves
    spmm_kernel<<<10000, 256, 0, stream>>>(rpA, sortedA, X0s, X1s,
                                           rpB, sortedB, X0t, X1t);
    spmm_kernel<<<10000, 256, 0, stream>>>(rpA, sortedA, X1s, X2s,
                                           rpB, sortedB, X1t, X2t);

    combine_kernel<<<dim3(313, 4), 256, 0, stream>>>(X2s, X0s, X2t, X0t, hadBK);

    gemm1_kernel<<<dim3(8, NZ_), 512, 0, stream>>>(hadBK, W1, part);
    reduce_kernel<<<1024, 256, 0, stream>>>(part, b1, h1);
    gemm23_kernel<<<B_, 128, 0, stream>>>(h1, W2, b2, W3, b3, out);
}

// Round 8
// 432.905 us; speedup vs baseline: 8.4529x; 1.0078x over previous
//
#include <hip/hip_runtime.h>
#include <hip/hip_fp16.h>

#define G_   20000
#define B_   256
#define NNZ_ 640000
#define KCH_ 640       // gemm1 split-K chunk (20 steps of 32; z=31 does 5)
#define NZ_  32        // split-K factor
#define NBUK 157       // ceil(20000/128) row buckets of 128 rows
#define BCAP 4608      // per-bucket segment capacity (avg 4076, >8 sigma slack)
#define EPB  4000      // binsort entries per block (160 blocks x 4000 = NNZ)

typedef float f4 __attribute__((ext_vector_type(4)));
typedef _Float16 h8 __attribute__((ext_vector_type(8)));

// ---------------- zero scratch ------------------------------------------
__global__ __launch_bounds__(256) void zero_kernel(unsigned int* p, int n) {
    int i = blockIdx.x * 256 + threadIdx.x;
    if (i < n) p[i] = 0u;
}

// ---------------- embed + transpose: [B,G] f32 -> [G,B] f16 --------------
__global__ __launch_bounds__(256) void embed_kernel(
        const float* __restrict__ xsamp, const float* __restrict__ xtf,
        const float* __restrict__ em, const float* __restrict__ bm,
        const float* __restrict__ ee, const float* __restrict__ be,
        __half* __restrict__ X0s, __half* __restrict__ X0t) {
    __shared__ float lds[64][65];       // [b][g]
    const int t  = threadIdx.x;
    const int gb = blockIdx.x * 64, bb = blockIdx.y * 64;
    const float a_m = em[0], c_m = bm[0], a_e = ee[0], c_e = be[0];
    const int gl = t & 63, brow0 = t >> 6;     // load mapping
    const int cl = t & 31, row0  = t >> 5;     // store mapping
    const int g_l = gb + gl;
#pragma unroll
    for (int r = 0; r < 16; r++) {
        int bl = brow0 + r * 4;
        float v = 0.f;
        if (g_l < G_) v = xsamp[(size_t)(bb + bl) * G_ + g_l];
        lds[bl][gl] = fmaxf(a_m * v + c_m, 0.f);
    }
    __syncthreads();
#pragma unroll
    for (int r = 0; r < 8; r++) {
        int gl2 = row0 + r * 8;
        int g = gb + gl2;
        if (g < G_) {
            __half2 hv = __floats2half2_rn(lds[cl * 2][gl2], lds[cl * 2 + 1][gl2]);
            *(__half2*)(X0s + (size_t)g * B_ + bb + cl * 2) = hv;
        }
    }
    __syncthreads();
#pragma unroll
    for (int r = 0; r < 16; r++) {
        int bl = brow0 + r * 4;
        float v = 0.f;
        if (g_l < G_) v = xtf[(size_t)(bb + bl) * G_ + g_l];
        lds[bl][gl] = fmaxf(a_e * v + c_e, 0.f);
    }
    __syncthreads();
#pragma unroll
    for (int r = 0; r < 8; r++) {
        int gl2 = row0 + r * 8;
        int g = gb + gl2;
        if (g < G_) {
            __half2 hv = __floats2half2_rn(lds[cl * 2][gl2], lds[cl * 2 + 1][gl2]);
            *(__half2*)(X0t + (size_t)g * B_ + bb + cl * 2) = hv;
        }
    }
}

// ---------------- pass 1: bucket sort COO into 128-row bins --------------
// meta.x = (rowInBucket<<24) | col*512 ; meta.y = f32 bits of 0.9*val.
__global__ __launch_bounds__(256) void binsort_kernel(
        const int* __restrict__ rA, const int* __restrict__ cA, const float* __restrict__ vA,
        const int* __restrict__ rB, const int* __restrict__ cB, const float* __restrict__ vB,
        int2* __restrict__ metaA, int* __restrict__ cntA,
        int2* __restrict__ metaB, int* __restrict__ cntB) {
    __shared__ int2 stage[EPB];                 // 32000 B
    __shared__ unsigned char bkid[EPB];         // 4000 B
    __shared__ int hist[NBUK], lstart[NBUK], gbase[NBUK];
    const int t = threadIdx.x;
    const int base = blockIdx.x * EPB;
    const int* rows; const int* colsp; const float* valsp; int2* meta; int* cnt;
    if (blockIdx.y == 0) { rows = rA; colsp = cA; valsp = vA; meta = metaA; cnt = cntA; }
    else                 { rows = rB; colsp = cB; valsp = vB; meta = metaB; cnt = cntB; }

    for (int i = t; i < NBUK; i += 256) hist[i] = 0;
    __syncthreads();
    for (int i = t; i < EPB; i += 256)
        atomicAdd(&hist[rows[base + i] >> 7], 1);
    __syncthreads();
    if (t == 0) {
        int s = 0;
        for (int b = 0; b < NBUK; b++) { lstart[b] = s; s += hist[b]; }
    }
    __syncthreads();
    if (t < NBUK) hist[t] = lstart[t];          // reuse hist as cursor
    __syncthreads();
    for (int i = t; i < EPB; i += 256) {
        int r = rows[base + i];
        int c = colsp[base + i];
        float v = valsp[base + i];
        int b = r >> 7;
        int p = atomicAdd(&hist[b], 1);
        stage[p] = make_int2(((r & 127) << 24) | (c * (B_ * 2)),
                             __float_as_int(0.9f * v));
        bkid[p] = (unsigned char)b;
    }
    __syncthreads();
    if (t < NBUK) gbase[t] = atomicAdd(&cnt[t], hist[t] - lstart[t]);
    __syncthreads();
    for (int i = t; i < EPB; i += 256) {
        int b = bkid[i];
        meta[(size_t)b * BCAP + gbase[b] + (i - lstart[b])] = stage[i];
    }
}

// ---------------- pass 2: composite-key counting sort -> CSR -------------
// key = rowInBucket*16 | colbucket (col>>11). One block per (bucket, matrix).
__global__ __launch_bounds__(256) void rowsort_kernel(
        const int2* __restrict__ metaA, const int* __restrict__ cntA,
        int2* __restrict__ sortedA, int* __restrict__ rpA,
        const int2* __restrict__ metaB, const int* __restrict__ cntB,
        int2* __restrict__ sortedB, int* __restrict__ rpB) {
    __shared__ int2 stage[BCAP];                // 36864 B
    __shared__ int2 sorted[BCAP];               // 36864 B
    __shared__ int hist[2048];                  // 8192 B (counts->starts->cursors)
    __shared__ int scanbuf[256];
    __shared__ int rowstart[128];
    __shared__ int carr[NBUK];
    const int t = threadIdx.x;
    const int buk = blockIdx.x;
    const int2* meta; const int* cnt; int2* outp; int* rp;
    if (blockIdx.y == 0) { meta = metaA; cnt = cntA; outp = sortedA; rp = rpA; }
    else                 { meta = metaB; cnt = cntB; outp = sortedB; rp = rpB; }

    if (t < NBUK) carr[t] = cnt[t];
    for (int i = t; i < 2048; i += 256) hist[i] = 0;
    __syncthreads();
    int bukStart = 0;
    const int nE = carr[buk];
    for (int b = 0; b < buk; b++) bukStart += carr[b];

    const int2* mp = meta + (size_t)buk * BCAP;
    for (int i = t; i < nE; i += 256) {
        int2 m = mp[i];
        stage[i] = m;
        unsigned ux = (unsigned)m.x;
        int key = ((ux >> 24) << 4) | ((ux & 0xFFFFFF) >> 20);  // row*16 | c>>11
        atomicAdd(&hist[key], 1);
    }
    __syncthreads();
    int loc[8];
    {
        int s = 0;
#pragma unroll
        for (int i = 0; i < 8; i++) { loc[i] = s; s += hist[t * 8 + i]; }
        scanbuf[t] = s;
    }
    __syncthreads();
    for (int off = 1; off < 256; off <<= 1) {
        int v = scanbuf[t];
        int add = (t >= off) ? scanbuf[t - off] : 0;
        __syncthreads();
        scanbuf[t] = v + add;
        __syncthreads();
    }
    {
        int pre = (t == 0) ? 0 : scanbuf[t - 1];
#pragma unroll
        for (int i = 0; i < 8; i++) hist[t * 8 + i] = pre + loc[i];
    }
    __syncthreads();
    if (t < 128) rowstart[t] = hist[t << 4];    // row start before cursor bump
    __syncthreads();
    for (int i = t; i < nE; i += 256) {
        int2 m = stage[i];
        unsigned ux = (unsigned)m.x;
        int key = ((ux >> 24) << 4) | ((ux & 0xFFFFFF) >> 20);
        int p = atomicAdd(&hist[key], 1);
        sorted[p] = make_int2(m.x & 0xFFFFFF, m.y);
    }
    __syncthreads();
    for (int i = t; i < nE; i += 256)
        outp[bukStart + i] = sorted[i];
    if (t < 128) {
        int g = buk * 128 + t;
        if (g < G_) rp[g] = bukStart + rowstart[t];
    }
    if (buk == NBUK - 1 && t == 0) rp[G_] = bukStart + nE;
}

// ---------------- SPMM f16, full row per wave, unroll-8 MLP --------------
// grid 10000; combo = bid&1 -> matrix. Wave owns row g (64 lanes x 8B).
// n wave-uniform; 8 gathers in flight per wave to hide L2/L3 latency.
__global__ __launch_bounds__(256) void spmm_kernel(
        const int* __restrict__ rpA, const int2* __restrict__ metaA,
        const __half* __restrict__ xinA, __half* __restrict__ xoutA,
        const int* __restrict__ rpB, const int2* __restrict__ metaB,
        const __half* __restrict__ xinB, __half* __restrict__ xoutB) {
    const int bid   = blockIdx.x;
    const int combo = bid & 1;
    const int t = threadIdx.x;
    const int wave = t >> 6, lane = t & 63;
    const int g = (bid >> 1) * 4 + wave;
    const int* rp; const int2* meta; const __half* xin; __half* xout;
    if (combo == 0) { rp = rpA; meta = metaA; xin = xinA; xout = xoutA; }
    else            { rp = rpB; meta = metaB; xin = xinB; xout = xoutB; }
    const int beg = __builtin_amdgcn_readfirstlane(rp[g]);
    const int n   = __builtin_amdgcn_readfirstlane(rp[g + 1]) - beg;
    const char* xb = (const char*)xin + lane * 8;
    float a0 = 0.f, a1 = 0.f, a2 = 0.f, a3 = 0.f;
    int e = 0;
    for (; e + 8 <= n; e += 8) {
        int2 m[8];
        uint2 r[8];
#pragma unroll
        for (int j = 0; j < 8; j++) m[j] = meta[beg + e + j];
#pragma unroll
        for (int j = 0; j < 8; j++) r[j] = *(const uint2*)(xb + m[j].x);
#pragma unroll
        for (int j = 0; j < 8; j++) {
            float v = __int_as_float(m[j].y);
            float2 l = __half22float2(*(__half2*)&r[j].x);
            float2 h = __half22float2(*(__half2*)&r[j].y);
            a0 = fmaf(v, l.x, a0); a1 = fmaf(v, l.y, a1);
            a2 = fmaf(v, h.x, a2); a3 = fmaf(v, h.y, a3);
        }
    }
    if (e + 4 <= n) {
        int2 m[4];
        uint2 r[4];
#pragma unroll
        for (int j = 0; j < 4; j++) m[j] = meta[beg + e + j];
#pragma unroll
        for (int j = 0; j < 4; j++) r[j] = *(const uint2*)(xb + m[j].x);
#pragma unroll
        for (int j = 0; j < 4; j++) {
            float v = __int_as_float(m[j].y);
            float2 l = __half22float2(*(__half2*)&r[j].x);
            float2 h = __half22float2(*(__half2*)&r[j].y);
            a0 = fmaf(v, l.x, a0); a1 = fmaf(v, l.y, a1);
            a2 = fmaf(v, h.x, a2); a3 = fmaf(v, h.y, a3);
        }
        e += 4;
    }
    for (; e < n; ++e) {
        int2 m = meta[beg + e];
        float v = __int_as_float(m.y);
        uint2 r = *(const uint2*)(xb + m.x);
        float2 l = __half22float2(*(__half2*)&r.x), h = __half22float2(*(__half2*)&r.y);
        a0 = fmaf(v, l.x, a0); a1 = fmaf(v, l.y, a1);
        a2 = fmaf(v, h.x, a2); a3 = fmaf(v, h.y, a3);
    }
    __half2 o0 = __floats2half2_rn(a0, a1);
    __half2 o1 = __floats2half2_rn(a2, a3);
    uint2 ov;
    ov.x = *(unsigned*)&o0;
    ov.y = *(unsigned*)&o1;
    *(uint2*)((char*)xout + (size_t)g * (B_ * 2) + lane * 8) = ov;
}

// ---------------- combine + transpose + f16: -> had[b][g] ----------------
__global__ __launch_bounds__(256) void combine_kernel(
        const __half* __restrict__ X2s, const __half* __restrict__ X0s,
        const __half* __restrict__ X2t, const __half* __restrict__ X0t,
        __half* __restrict__ hadBK) {
    __shared__ float lds[64][65];       // [g][b]
    const int t = threadIdx.x;
    const int gb = blockIdx.x * 64, bb = blockIdx.y * 64;
    const int cl = t & 31, row0 = t >> 5;
#pragma unroll
    for (int r = 0; r < 8; r++) {
        int gl = row0 + r * 8;
        int g = gb + gl;
        float px = 0.f, py = 0.f;
        if (g < G_) {
            size_t idx = (size_t)g * B_ + bb + cl * 2;
            float2 x2s = __half22float2(*(const __half2*)(X2s + idx));
            float2 x0s = __half22float2(*(const __half2*)(X0s + idx));
            float2 x2t = __half22float2(*(const __half2*)(X2t + idx));
            float2 x0t = __half22float2(*(const __half2*)(X0t + idx));
            px = (x2s.x + 0.1f * x0s.x) * (x2t.x + 0.1f * x0t.x);
            py = (x2s.y + 0.1f * x0s.y) * (x2t.y + 0.1f * x0t.y);
        }
        lds[gl][cl * 2]     = px;
        lds[gl][cl * 2 + 1] = py;
    }
    __syncthreads();
#pragma unroll
    for (int r = 0; r < 8; r++) {
        int bl = row0 + r * 8;
        int g0 = gb + cl * 2;
        if (g0 < G_) {
            __half2 hv = __floats2half2_rn(lds[cl * 2][bl], lds[cl * 2 + 1][bl]);
            *(__half2*)(hadBK + (size_t)(bb + bl) * G_ + g0) = hv;
        }
    }
}

// ---------------- GEMM1 MFMA f16, dbuf LDS (1 barrier/step) --------------
// tile 256(b) x 128(o) x BK32, 512 thr = 8 waves; reg prefetch + LDS[2]
// parity buffers: stage s+1 overlaps compute s; single barrier per step.
__global__ __launch_bounds__(512) void gemm1_kernel(
        const __half* __restrict__ hadBK, const float* __restrict__ W1,
        float* __restrict__ part) {
    __shared__ _Float16 a_lds[2][256][40];   // 40960 B
    __shared__ _Float16 b_lds[2][128][40];   // 20480 B
    const int t = threadIdx.x;
    const int lane = t & 63, wid = t >> 6;
    const int wm = wid >> 1, wn = wid & 1;
    const int l15 = lane & 15, l4 = lane >> 4;
    const int ob = blockIdx.x * 128;
    const int kb = blockIdx.y * KCH_;
    int kend = kb + KCH_; if (kend > G_) kend = G_;
    const int nsteps = (kend - kb) >> 5;       // 20, or 5 at z=31
    const int ar = t >> 1, ah = t & 1;
    const int br = t >> 2, bs = t & 3;
    const _Float16* hadH = (const _Float16*)hadBK;
    const _Float16* asrc = hadH + (size_t)ar * G_ + ah * 16;
    const float*    bsrc = W1 + (size_t)(ob + br) * G_ + bs * 8;
    f4 acc[4][4] = {};
    // prologue: load step 0 -> regs -> LDS[0]
    h8 ra0 = *(const h8*)(asrc + kb);
    h8 ra1 = *(const h8*)(asrc + kb + 8);
    f4 rb0 = *(const f4*)(bsrc + kb);
    f4 rb1 = *(const f4*)(bsrc + kb + 4);
    *(h8*)&a_lds[0][ar][ah * 16]     = ra0;
    *(h8*)&a_lds[0][ar][ah * 16 + 8] = ra1;
    {
        h8 h;
        h[0] = (_Float16)rb0[0]; h[1] = (_Float16)rb0[1];
        h[2] = (_Float16)rb0[2]; h[3] = (_Float16)rb0[3];
        h[4] = (_Float16)rb1[0]; h[5] = (_Float16)rb1[1];
        h[6] = (_Float16)rb1[2]; h[7] = (_Float16)rb1[3];
        *(h8*)&b_lds[0][br][bs * 8] = h;
    }
    __syncthreads();
    int p = 0;
    for (int s = 0; s < nsteps; ++s) {
        // issue next step's global loads (complete during this step's MFMAs)
        if (s + 1 < nsteps) {
            const int k1 = kb + (s + 1) * 32;
            ra0 = *(const h8*)(asrc + k1);
            ra1 = *(const h8*)(asrc + k1 + 8);
            rb0 = *(const f4*)(bsrc + k1);
            rb1 = *(const f4*)(bsrc + k1 + 4);
        }
        h8 af[4], bf[4];
#pragma unroll
        for (int m = 0; m < 4; m++)
            af[m] = *(const h8*)&a_lds[p][wm * 64 + m * 16 + l15][l4 * 8];
#pragma unroll
        for (int n = 0; n < 4; n++)
            bf[n] = *(const h8*)&b_lds[p][wn * 64 + n * 16 + l15][l4 * 8];
#pragma unroll
        for (int m = 0; m < 4; m++)
#pragma unroll
            for (int n = 0; n < 4; n++)
                acc[m][n] = __builtin_amdgcn_mfma_f32_16x16x32_f16(
                    af[m], bf[n], acc[m][n], 0, 0, 0);
        if (s + 1 < nsteps) {
            // stage s+1 into the other buffer; one barrier per step
            *(h8*)&a_lds[p ^ 1][ar][ah * 16]     = ra0;
            *(h8*)&a_lds[p ^ 1][ar][ah * 16 + 8] = ra1;
            h8 h;
            h[0] = (_Float16)rb0[0]; h[1] = (_Float16)rb0[1];
            h[2] = (_Float16)rb0[2]; h[3] = (_Float16)rb0[3];
            h[4] = (_Float16)rb1[0]; h[5] = (_Float16)rb1[1];
            h[6] = (_Float16)rb1[2]; h[7] = (_Float16)rb1[3];
            *(h8*)&b_lds[p ^ 1][br][bs * 8] = h;
            __syncthreads();
            p ^= 1;
        }
    }
    const size_t zoff = (size_t)blockIdx.y * (B_ * 1024);
#pragma unroll
    for (int m = 0; m < 4; m++)
#pragma unroll
        for (int n = 0; n < 4; n++)
#pragma unroll
            for (int j = 0; j < 4; j++) {
                int b = wm * 64 + m * 16 + l4 * 4 + j;
                int o = ob + wn * 64 + n * 16 + l15;
                part[zoff + (size_t)b * 1024 + o] = acc[m][n][j];
            }
}

// ---------------- fused reduce+bias+relu + GEMM2 (relu) + GEMM3 ----------
__global__ __launch_bounds__(128) void gemm23_kernel(
        const float* __restrict__ part, const float* __restrict__ b1,
        const float* __restrict__ W2, const float* __restrict__ b2,
        const float* __restrict__ W3, const float* __restrict__ b3,
        float* __restrict__ out) {
    __shared__ float h1row[1024];
    __shared__ float h2[128];
    const int b = blockIdx.x, t = threadIdx.x;
    // split-K reduce for this batch row: h1row[o] = relu(sum_z part[z][b][o] + b1[o])
#pragma unroll
    for (int seg = 0; seg < 2; seg++) {
        int o4 = t + seg * 128;               // f4 index 0..255
        f4 s = {0.f, 0.f, 0.f, 0.f};
        for (int z = 0; z < NZ_; z++)
            s += ((const f4*)(part + (size_t)z * 262144 + (size_t)b * 1024))[o4];
        s += ((const f4*)b1)[o4];
        f4 r;
        r[0] = fmaxf(s[0], 0.f); r[1] = fmaxf(s[1], 0.f);
        r[2] = fmaxf(s[2], 0.f); r[3] = fmaxf(s[3], 0.f);
        ((f4*)h1row)[o4] = r;
    }
    __syncthreads();
    {
        float acc = b2[t];
        const f4* w  = (const f4*)(W2 + (size_t)t * 1024);
        const f4* hr = (const f4*)h1row;
        for (int k = 0; k < 256; k++) {
            f4 wv = w[k], hv = hr[k];
            acc += wv[0] * hv[0] + wv[1] * hv[1] + wv[2] * hv[2] + wv[3] * hv[3];
        }
        h2[t] = fmaxf(acc, 0.f);
    }
    __syncthreads();
    if (t < 33) {
        float acc = b3[t];
        const f4* w  = (const f4*)(W3 + (size_t)t * 128);
        const f4* hv = (const f4*)h2;
#pragma unroll
        for (int k = 0; k < 32; k++) {
            f4 a = w[k], x = hv[k];
            acc += a[0] * x[0] + a[1] * x[1] + a[2] * x[2] + a[3] * x[3];
        }
        out[b * 33 + t] = acc;
    }
}

extern "C" void kernel_launch(void* const* d_in, const int* in_sizes, int n_in,
                              void* d_out, int out_size, void* d_ws, size_t ws_size,
                              hipStream_t stream) {
    const float* x_sample  = (const float*)d_in[0];
    const float* x_TF      = (const float*)d_in[1];
    const int*   adj_rows  = (const int*)d_in[2];
    const int*   adj_cols  = (const int*)d_in[3];
    const float* adj_vals  = (const float*)d_in[4];
    const int*   adjT_rows = (const int*)d_in[5];
    const int*   adjT_cols = (const int*)d_in[6];
    const float* adjT_vals = (const float*)d_in[7];
    const float* emb_mut   = (const float*)d_in[8];
    const float* bias_mut  = (const float*)d_in[9];
    const float* emb_exp   = (const float*)d_in[10];
    const float* bias_exp  = (const float*)d_in[11];
    const float* W1 = (const float*)d_in[12];
    const float* b1 = (const float*)d_in[13];
    const float* W2 = (const float*)d_in[14];
    const float* b2 = (const float*)d_in[15];
    const float* W3 = (const float*)d_in[16];
    const float* b3 = (const float*)d_in[17];
    float* out = (float*)d_out;

    // ---- workspace layout (~120 MB) ----
    char* w = (char*)d_ws;
    auto alloc = [&](size_t bytes) {
        char* p = w; w += (bytes + 255) & ~(size_t)255; return p;
    };
    __half* X0s = (__half*)alloc(5120000 * 2);
    __half* X1s = (__half*)alloc(5120000 * 2);
    __half* X2s = (__half*)alloc(5120000 * 2);
    __half* X0t = (__half*)alloc(5120000 * 2);
    __half* X1t = (__half*)alloc(5120000 * 2);
    __half* X2t = (__half*)alloc(5120000 * 2);
    float*  part = (float*)alloc((size_t)NZ_ * 262144 * 4);   // 33.5 MB
    int2*   metaA   = (int2*)alloc((size_t)NBUK * BCAP * 8);  // 5.79 MB bucketed
    int2*   metaB   = (int2*)alloc((size_t)NBUK * BCAP * 8);
    int2*   sortedA = (int2*)alloc((size_t)(NNZ_ + 128) * 8); // 5.12 MB CSR-sorted
    int2*   sortedB = (int2*)alloc((size_t)(NNZ_ + 128) * 8);
    int*    cnt   = (int*)alloc(2 * NBUK * 4);
    int*    cntA  = cnt;
    int*    cntB  = cnt + NBUK;
    int*    rpA   = (int*)alloc(20001 * 4);
    int*    rpB   = (int*)alloc(20001 * 4);
    __half* hadBK = X1s;    // overlay: X1s dead after spmm iter 2

    zero_kernel<<<2, 256, 0, stream>>>((unsigned int*)cnt, 2 * NBUK);

    embed_kernel<<<dim3(313, 4), 256, 0, stream>>>(
        x_sample, x_TF, emb_mut, bias_mut, emb_exp, bias_exp, X0s, X0t);

    // two-pass coalesced CSR build (row-grouped, col-sorted within row)
    binsort_kernel<<<dim3(160, 2), 256, 0, stream>>>(
        adj_rows, adj_cols, adj_vals, adjT_rows, adjT_cols, adjT_vals,
        metaA, cntA, metaB, cntB);
    rowsort_kernel<<<dim3(NBUK, 2), 256, 0, stream>>>(
        metaA, cntA, sortedA, rpA, metaB, cntB, sortedB, rpB);

    // K = 2 PPR iterations (0.9 folded into vals), full-row waves
    spmm_kernel<<<10000, 256, 0, stream>>>(rpA, sortedA, X0s, X1s,
                                           rpB, sortedB, X0t, X1t);
    spmm_kernel<<<10000, 256, 0, stream>>>(rpA, sortedA, X1s, X2s,
                                           rpB, sortedB, X1t, X2t);

    combine_kernel<<<dim3(313, 4), 256, 0, stream>>>(X2s, X0s, X2t, X0t, hadBK);

    gemm1_kernel<<<dim3(8, NZ_), 512, 0, stream>>>(hadBK, W1, part);
    gemm23_kernel<<<B_, 128, 0, stream>>>(part, b1, W2, b2, W3, b3, out);
}

// Round 9
// 410.029 us; speedup vs baseline: 8.9245x; 1.0558x over previous
//
#include <hip/hip_runtime.h>
#include <hip/hip_fp16.h>

#define G_   20000
#define B_   256
#define NNZ_ 640000
#define KCH_ 640       // gemm1 split-K chunk (20 steps of 32; z=31 does 5)
#define NZ_  32        // split-K factor
#define NBUK 157       // ceil(20000/128) row buckets of 128 rows
#define BCAP 4608      // per-bucket segment capacity (avg 4076, >8 sigma slack)
#define EPB  4000      // binsort entries per block (160 blocks x 4000 = NNZ)

typedef float f4 __attribute__((ext_vector_type(4)));
typedef _Float16 h8 __attribute__((ext_vector_type(8)));

// ---------------- embed + transpose: [B,G] f32 -> [G,B] f16 --------------
// Block (0,0) also zeroes the binsort counters (saves a dispatch).
__global__ __launch_bounds__(256) void embed_kernel(
        const float* __restrict__ xsamp, const float* __restrict__ xtf,
        const float* __restrict__ em, const float* __restrict__ bm,
        const float* __restrict__ ee, const float* __restrict__ be,
        __half* __restrict__ X0s, __half* __restrict__ X0t,
        int* __restrict__ cnt) {
    __shared__ float lds[64][65];       // [b][g]
    const int t  = threadIdx.x;
    if (blockIdx.x == 0 && blockIdx.y == 0)
        for (int i = t; i < 2 * NBUK; i += 256) cnt[i] = 0;
    const int gb = blockIdx.x * 64, bb = blockIdx.y * 64;
    const float a_m = em[0], c_m = bm[0], a_e = ee[0], c_e = be[0];
    const int gl = t & 63, brow0 = t >> 6;     // load mapping
    const int cl = t & 31, row0  = t >> 5;     // store mapping
    const int g_l = gb + gl;
#pragma unroll
    for (int r = 0; r < 16; r++) {
        int bl = brow0 + r * 4;
        float v = 0.f;
        if (g_l < G_) v = xsamp[(size_t)(bb + bl) * G_ + g_l];
        lds[bl][gl] = fmaxf(a_m * v + c_m, 0.f);
    }
    __syncthreads();
#pragma unroll
    for (int r = 0; r < 8; r++) {
        int gl2 = row0 + r * 8;
        int g = gb + gl2;
        if (g < G_) {
            __half2 hv = __floats2half2_rn(lds[cl * 2][gl2], lds[cl * 2 + 1][gl2]);
            *(__half2*)(X0s + (size_t)g * B_ + bb + cl * 2) = hv;
        }
    }
    __syncthreads();
#pragma unroll
    for (int r = 0; r < 16; r++) {
        int bl = brow0 + r * 4;
        float v = 0.f;
        if (g_l < G_) v = xtf[(size_t)(bb + bl) * G_ + g_l];
        lds[bl][gl] = fmaxf(a_e * v + c_e, 0.f);
    }
    __syncthreads();
#pragma unroll
    for (int r = 0; r < 8; r++) {
        int gl2 = row0 + r * 8;
        int g = gb + gl2;
        if (g < G_) {
            __half2 hv = __floats2half2_rn(lds[cl * 2][gl2], lds[cl * 2 + 1][gl2]);
            *(__half2*)(X0t + (size_t)g * B_ + bb + cl * 2) = hv;
        }
    }
}

// ---------------- pass 1: bucket sort COO into 128-row bins --------------
// meta.x = (rowInBucket<<24) | col*512 ; meta.y = f32 bits of 0.9*val.
__global__ __launch_bounds__(256) void binsort_kernel(
        const int* __restrict__ rA, const int* __restrict__ cA, const float* __restrict__ vA,
        const int* __restrict__ rB, const int* __restrict__ cB, const float* __restrict__ vB,
        int2* __restrict__ metaA, int* __restrict__ cntA,
        int2* __restrict__ metaB, int* __restrict__ cntB) {
    __shared__ int2 stage[EPB];                 // 32000 B
    __shared__ unsigned char bkid[EPB];         // 4000 B
    __shared__ int hist[NBUK], lstart[NBUK], gbase[NBUK];
    const int t = threadIdx.x;
    const int base = blockIdx.x * EPB;
    const int* rows; const int* colsp; const float* valsp; int2* meta; int* cnt;
    if (blockIdx.y == 0) { rows = rA; colsp = cA; valsp = vA; meta = metaA; cnt = cntA; }
    else                 { rows = rB; colsp = cB; valsp = vB; meta = metaB; cnt = cntB; }

    for (int i = t; i < NBUK; i += 256) hist[i] = 0;
    __syncthreads();
    for (int i = t; i < EPB; i += 256)
        atomicAdd(&hist[rows[base + i] >> 7], 1);
    __syncthreads();
    if (t == 0) {
        int s = 0;
        for (int b = 0; b < NBUK; b++) { lstart[b] = s; s += hist[b]; }
    }
    __syncthreads();
    if (t < NBUK) hist[t] = lstart[t];          // reuse hist as cursor
    __syncthreads();
    for (int i = t; i < EPB; i += 256) {
        int r = rows[base + i];
        int c = colsp[base + i];
        float v = valsp[base + i];
        int b = r >> 7;
        int p = atomicAdd(&hist[b], 1);
        stage[p] = make_int2(((r & 127) << 24) | (c * (B_ * 2)),
                             __float_as_int(0.9f * v));
        bkid[p] = (unsigned char)b;
    }
    __syncthreads();
    if (t < NBUK) gbase[t] = atomicAdd(&cnt[t], hist[t] - lstart[t]);
    __syncthreads();
    for (int i = t; i < EPB; i += 256) {
        int b = bkid[i];
        meta[(size_t)b * BCAP + gbase[b] + (i - lstart[b])] = stage[i];
    }
}

// ---------------- pass 2: in-bucket counting sort -> exact CSR -----------
// 128-key counting sort (col-sort dropped: proven no-locality-gain r7).
__global__ __launch_bounds__(256) void rowsort_kernel(
        const int2* __restrict__ metaA, const int* __restrict__ cntA,
        int2* __restrict__ sortedA, int* __restrict__ rpA,
        const int2* __restrict__ metaB, const int* __restrict__ cntB,
        int2* __restrict__ sortedB, int* __restrict__ rpB) {
    __shared__ int2 stage[BCAP];                // 36864 B
    __shared__ int2 sorted[BCAP];               // 36864 B
    __shared__ int carr[NBUK];
    __shared__ int hist[128], lstart[128];
    const int t = threadIdx.x;
    const int buk = blockIdx.x;
    const int2* meta; const int* cnt; int2* outp; int* rp;
    if (blockIdx.y == 0) { meta = metaA; cnt = cntA; outp = sortedA; rp = rpA; }
    else                 { meta = metaB; cnt = cntB; outp = sortedB; rp = rpB; }

    if (t < NBUK) carr[t] = cnt[t];
    if (t < 128) hist[t] = 0;
    __syncthreads();
    int bukStart = 0;
    const int nE = carr[buk];
    for (int b = 0; b < buk; b++) bukStart += carr[b];

    const int2* mp = meta + (size_t)buk * BCAP;
    for (int i = t; i < nE; i += 256) {
        int2 m = mp[i];
        stage[i] = m;
        atomicAdd(&hist[(unsigned)m.x >> 24], 1);
    }
    __syncthreads();
    if (t == 0) {
        int s = 0;
        for (int r = 0; r < 128; r++) { lstart[r] = s; s += hist[r]; }
    }
    __syncthreads();
    if (t < 128) hist[t] = lstart[t];           // reuse as cursor
    __syncthreads();
    for (int i = t; i < nE; i += 256) {
        int2 m = stage[i];
        int r = (unsigned)m.x >> 24;
        int p = atomicAdd(&hist[r], 1);
        sorted[p] = make_int2(m.x & 0xFFFFFF, m.y);
    }
    __syncthreads();
    for (int i = t; i < nE; i += 256)
        outp[bukStart + i] = sorted[i];
    if (t < 128) {
        int g = buk * 128 + t;
        if (g < G_) rp[g] = bukStart + lstart[t];
    }
    if (buk == NBUK - 1 && t == 0) rp[G_] = bukStart + nE;
}

// ---------------- SPMM helpers -------------------------------------------
__device__ __forceinline__ void spmm_load8(const int2* __restrict__ mp, int base,
                                           int2* mm) {
#pragma unroll
    for (int j = 0; j < 8; j++) mm[j] = mp[base + j];
}
__device__ __forceinline__ void spmm_proc8(const int2* mm, const char* xb,
        float& a0, float& a1, float& a2, float& a3) {
    uint2 r[8];
#pragma unroll
    for (int j = 0; j < 8; j++) r[j] = *(const uint2*)(xb + mm[j].x);
#pragma unroll
    for (int j = 0; j < 8; j++) {
        float v = __int_as_float(mm[j].y);
        float2 l = __half22float2(*(__half2*)&r[j].x);
        float2 h = __half22float2(*(__half2*)&r[j].y);
        a0 = fmaf(v, l.x, a0); a1 = fmaf(v, l.y, a1);
        a2 = fmaf(v, h.x, a2); a3 = fmaf(v, h.y, a3);
    }
}

// ---------------- SPMM f16, full row/wave, meta-pipelined ----------------
// Temporal matrix split: bid<5000 -> A, else B (halves live gather set per
// XCD-L2). Wave owns row g; n wave-uniform; meta ping-pong (mA/mB) keeps
// next batch's s_loads in flight under current batch's gathers+FMA.
__global__ __launch_bounds__(256) void spmm_kernel(
        const int* __restrict__ rpA, const int2* __restrict__ metaA,
        const __half* __restrict__ xinA, __half* __restrict__ xoutA,
        const int* __restrict__ rpB, const int2* __restrict__ metaB,
        const __half* __restrict__ xinB, __half* __restrict__ xoutB) {
    const int bid = blockIdx.x;
    const int isB = bid >= 5000;
    const int idx = isB ? bid - 5000 : bid;
    const int t = threadIdx.x;
    const int wave = t >> 6, lane = t & 63;
    const int g = idx * 4 + wave;
    const int* rp; const int2* meta; const __half* xin; __half* xout;
    if (!isB) { rp = rpA; meta = metaA; xin = xinA; xout = xoutA; }
    else      { rp = rpB; meta = metaB; xin = xinB; xout = xoutB; }
    const int beg = __builtin_amdgcn_readfirstlane(rp[g]);
    const int n   = __builtin_amdgcn_readfirstlane(rp[g + 1]) - beg;
    const int2* mp = meta + beg;
    const char* xb = (const char*)xin + lane * 8;
    float a0 = 0.f, a1 = 0.f, a2 = 0.f, a3 = 0.f;
    const int nb = n >> 3;
    int2 mA[8], mB[8];
    if (nb > 0) spmm_load8(mp, 0, mA);
    int b2 = 0;
    while (b2 < nb) {
        if (b2 + 1 < nb) spmm_load8(mp, (b2 + 1) * 8, mB);
        spmm_proc8(mA, xb, a0, a1, a2, a3);
        b2++;
        if (b2 >= nb) break;
        if (b2 + 1 < nb) spmm_load8(mp, (b2 + 1) * 8, mA);
        spmm_proc8(mB, xb, a0, a1, a2, a3);
        b2++;
    }
    for (int e = nb * 8; e < n; ++e) {
        int2 m = mp[e];
        float v = __int_as_float(m.y);
        uint2 r = *(const uint2*)(xb + m.x);
        float2 l = __half22float2(*(__half2*)&r.x), h = __half22float2(*(__half2*)&r.y);
        a0 = fmaf(v, l.x, a0); a1 = fmaf(v, l.y, a1);
        a2 = fmaf(v, h.x, a2); a3 = fmaf(v, h.y, a3);
    }
    __half2 o0 = __floats2half2_rn(a0, a1);
    __half2 o1 = __floats2half2_rn(a2, a3);
    uint2 ov;
    ov.x = *(unsigned*)&o0;
    ov.y = *(unsigned*)&o1;
    *(uint2*)((char*)xout + (size_t)g * (B_ * 2) + lane * 8) = ov;
}

// ---------------- combine + transpose + f16: -> had[b][g] ----------------
__global__ __launch_bounds__(256) void combine_kernel(
        const __half* __restrict__ X2s, const __half* __restrict__ X0s,
        const __half* __restrict__ X2t, const __half* __restrict__ X0t,
        __half* __restrict__ hadBK) {
    __shared__ float lds[64][65];       // [g][b]
    const int t = threadIdx.x;
    const int gb = blockIdx.x * 64, bb = blockIdx.y * 64;
    const int cl = t & 31, row0 = t >> 5;
#pragma unroll
    for (int r = 0; r < 8; r++) {
        int gl = row0 + r * 8;
        int g = gb + gl;
        float px = 0.f, py = 0.f;
        if (g < G_) {
            size_t idx = (size_t)g * B_ + bb + cl * 2;
            float2 x2s = __half22float2(*(const __half2*)(X2s + idx));
            float2 x0s = __half22float2(*(const __half2*)(X0s + idx));
            float2 x2t = __half22float2(*(const __half2*)(X2t + idx));
            float2 x0t = __half22float2(*(const __half2*)(X0t + idx));
            px = (x2s.x + 0.1f * x0s.x) * (x2t.x + 0.1f * x0t.x);
            py = (x2s.y + 0.1f * x0s.y) * (x2t.y + 0.1f * x0t.y);
        }
        lds[gl][cl * 2]     = px;
        lds[gl][cl * 2 + 1] = py;
    }
    __syncthreads();
#pragma unroll
    for (int r = 0; r < 8; r++) {
        int bl = row0 + r * 8;
        int g0 = gb + cl * 2;
        if (g0 < G_) {
            __half2 hv = __floats2half2_rn(lds[cl * 2][bl], lds[cl * 2 + 1][bl]);
            *(__half2*)(hadBK + (size_t)(bb + bl) * G_ + g0) = hv;
        }
    }
}

// ---------------- GEMM1 MFMA f16, dbuf LDS (1 barrier/step) --------------
__global__ __launch_bounds__(512) void gemm1_kernel(
        const __half* __restrict__ hadBK, const float* __restrict__ W1,
        float* __restrict__ part) {
    __shared__ _Float16 a_lds[2][256][40];   // 40960 B
    __shared__ _Float16 b_lds[2][128][40];   // 20480 B
    const int t = threadIdx.x;
    const int lane = t & 63, wid = t >> 6;
    const int wm = wid >> 1, wn = wid & 1;
    const int l15 = lane & 15, l4 = lane >> 4;
    const int ob = blockIdx.x * 128;
    const int kb = blockIdx.y * KCH_;
    int kend = kb + KCH_; if (kend > G_) kend = G_;
    const int nsteps = (kend - kb) >> 5;       // 20, or 5 at z=31
    const int ar = t >> 1, ah = t & 1;
    const int br = t >> 2, bs = t & 3;
    const _Float16* hadH = (const _Float16*)hadBK;
    const _Float16* asrc = hadH + (size_t)ar * G_ + ah * 16;
    const float*    bsrc = W1 + (size_t)(ob + br) * G_ + bs * 8;
    f4 acc[4][4] = {};
    h8 ra0 = *(const h8*)(asrc + kb);
    h8 ra1 = *(const h8*)(asrc + kb + 8);
    f4 rb0 = *(const f4*)(bsrc + kb);
    f4 rb1 = *(const f4*)(bsrc + kb + 4);
    *(h8*)&a_lds[0][ar][ah * 16]     = ra0;
    *(h8*)&a_lds[0][ar][ah * 16 + 8] = ra1;
    {
        h8 h;
        h[0] = (_Float16)rb0[0]; h[1] = (_Float16)rb0[1];
        h[2] = (_Float16)rb0[2]; h[3] = (_Float16)rb0[3];
        h[4] = (_Float16)rb1[0]; h[5] = (_Float16)rb1[1];
        h[6] = (_Float16)rb1[2]; h[7] = (_Float16)rb1[3];
        *(h8*)&b_lds[0][br][bs * 8] = h;
    }
    __syncthreads();
    int p = 0;
    for (int s = 0; s < nsteps; ++s) {
        if (s + 1 < nsteps) {
            const int k1 = kb + (s + 1) * 32;
            ra0 = *(const h8*)(asrc + k1);
            ra1 = *(const h8*)(asrc + k1 + 8);
            rb0 = *(const f4*)(bsrc + k1);
            rb1 = *(const f4*)(bsrc + k1 + 4);
        }
        h8 af[4], bf[4];
#pragma unroll
        for (int m = 0; m < 4; m++)
            af[m] = *(const h8*)&a_lds[p][wm * 64 + m * 16 + l15][l4 * 8];
#pragma unroll
        for (int n = 0; n < 4; n++)
            bf[n] = *(const h8*)&b_lds[p][wn * 64 + n * 16 + l15][l4 * 8];
#pragma unroll
        for (int m = 0; m < 4; m++)
#pragma unroll
            for (int n = 0; n < 4; n++)
                acc[m][n] = __builtin_amdgcn_mfma_f32_16x16x32_f16(
                    af[m], bf[n], acc[m][n], 0, 0, 0);
        if (s + 1 < nsteps) {
            *(h8*)&a_lds[p ^ 1][ar][ah * 16]     = ra0;
            *(h8*)&a_lds[p ^ 1][ar][ah * 16 + 8] = ra1;
            h8 h;
            h[0] = (_Float16)rb0[0]; h[1] = (_Float16)rb0[1];
            h[2] = (_Float16)rb0[2]; h[3] = (_Float16)rb0[3];
            h[4] = (_Float16)rb1[0]; h[5] = (_Float16)rb1[1];
            h[6] = (_Float16)rb1[2]; h[7] = (_Float16)rb1[3];
            *(h8*)&b_lds[p ^ 1][br][bs * 8] = h;
            __syncthreads();
            p ^= 1;
        }
    }
    const size_t zoff = (size_t)blockIdx.y * (B_ * 1024);
#pragma unroll
    for (int m = 0; m < 4; m++)
#pragma unroll
        for (int n = 0; n < 4; n++)
#pragma unroll
            for (int j = 0; j < 4; j++) {
                int b = wm * 64 + m * 16 + l4 * 4 + j;
                int o = ob + wn * 64 + n * 16 + l15;
                part[zoff + (size_t)b * 1024 + o] = acc[m][n][j];
            }
}

// ---------------- fused reduce+bias+relu + GEMM2 (relu) + GEMM3 ----------
// 256 threads: GEMM2's k-range split across 2 threads per output.
__global__ __launch_bounds__(256) void gemm23_kernel(
        const float* __restrict__ part, const float* __restrict__ b1,
        const float* __restrict__ W2, const float* __restrict__ b2,
        const float* __restrict__ W3, const float* __restrict__ b3,
        float* __restrict__ out) {
    __shared__ float h1row[1024];
    __shared__ float h2p[2][128];
    const int b = blockIdx.x, t = threadIdx.x;
    {   // split-K reduce: h1row = relu(sum_z part[z][b][:] + b1)
        f4 s = {0.f, 0.f, 0.f, 0.f};
        const float* pb = part + (size_t)b * 1024;
        for (int z = 0; z < NZ_; z++)
            s += ((const f4*)(pb + (size_t)z * 262144))[t];
        s += ((const f4*)b1)[t];
        f4 r;
        r[0] = fmaxf(s[0], 0.f); r[1] = fmaxf(s[1], 0.f);
        r[2] = fmaxf(s[2], 0.f); r[3] = fmaxf(s[3], 0.f);
        ((f4*)h1row)[t] = r;
    }
    __syncthreads();
    {   // GEMM2: output o = t&127, k-half = t>>7
        const int o = t & 127, hh = t >> 7;
        float acc = 0.f;
        const f4* w  = (const f4*)(W2 + (size_t)o * 1024 + hh * 512);
        const f4* hr = (const f4*)(h1row + hh * 512);
        for (int k = 0; k < 128; k++) {
            f4 wv = w[k], hv = hr[k];
            acc += wv[0] * hv[0] + wv[1] * hv[1] + wv[2] * hv[2] + wv[3] * hv[3];
        }
        h2p[hh][o] = acc;
    }
    __syncthreads();
    if (t < 128) h2p[0][t] = fmaxf(h2p[0][t] + h2p[1][t] + b2[t], 0.f);
    __syncthreads();
    if (t < 33) {
        float acc = b3[t];
        const f4* w  = (const f4*)(W3 + (size_t)t * 128);
        const f4* hv = (const f4*)h2p[0];
#pragma unroll
        for (int k = 0; k < 32; k++) {
            f4 a = w[k], x = hv[k];
            acc += a[0] * x[0] + a[1] * x[1] + a[2] * x[2] + a[3] * x[3];
        }
        out[b * 33 + t] = acc;
    }
}

extern "C" void kernel_launch(void* const* d_in, const int* in_sizes, int n_in,
                              void* d_out, int out_size, void* d_ws, size_t ws_size,
                              hipStream_t stream) {
    const float* x_sample  = (const float*)d_in[0];
    const float* x_TF      = (const float*)d_in[1];
    const int*   adj_rows  = (const int*)d_in[2];
    const int*   adj_cols  = (const int*)d_in[3];
    const float* adj_vals  = (const float*)d_in[4];
    const int*   adjT_rows = (const int*)d_in[5];
    const int*   adjT_cols = (const int*)d_in[6];
    const float* adjT_vals = (const float*)d_in[7];
    const float* emb_mut   = (const float*)d_in[8];
    const float* bias_mut  = (const float*)d_in[9];
    const float* emb_exp   = (const float*)d_in[10];
    const float* bias_exp  = (const float*)d_in[11];
    const float* W1 = (const float*)d_in[12];
    const float* b1 = (const float*)d_in[13];
    const float* W2 = (const float*)d_in[14];
    const float* b2 = (const float*)d_in[15];
    const float* W3 = (const float*)d_in[16];
    const float* b3 = (const float*)d_in[17];
    float* out = (float*)d_out;

    // ---- workspace layout (~120 MB) ----
    char* w = (char*)d_ws;
    auto alloc = [&](size_t bytes) {
        char* p = w; w += (bytes + 255) & ~(size_t)255; return p;
    };
    __half* X0s = (__half*)alloc(5120000 * 2);
    __half* X1s = (__half*)alloc(5120000 * 2);
    __half* X2s = (__half*)alloc(5120000 * 2);
    __half* X0t = (__half*)alloc(5120000 * 2);
    __half* X1t = (__half*)alloc(5120000 * 2);
    __half* X2t = (__half*)alloc(5120000 * 2);
    float*  part = (float*)alloc((size_t)NZ_ * 262144 * 4);   // 33.5 MB
    int2*   metaA   = (int2*)alloc((size_t)NBUK * BCAP * 8);  // 5.79 MB bucketed
    int2*   metaB   = (int2*)alloc((size_t)NBUK * BCAP * 8);
    int2*   sortedA = (int2*)alloc((size_t)(NNZ_ + 128) * 8); // 5.12 MB CSR-sorted
    int2*   sortedB = (int2*)alloc((size_t)(NNZ_ + 128) * 8);
    int*    cnt   = (int*)alloc(2 * NBUK * 4);
    int*    cntA  = cnt;
    int*    cntB  = cnt + NBUK;
    int*    rpA   = (int*)alloc(20001 * 4);
    int*    rpB   = (int*)alloc(20001 * 4);
    __half* hadBK = X1s;    // overlay: X1s dead after spmm iter 2

    // embed also zeroes cnt (block (0,0))
    embed_kernel<<<dim3(313, 4), 256, 0, stream>>>(
        x_sample, x_TF, emb_mut, bias_mut, emb_exp, bias_exp, X0s, X0t, cnt);

    // two-pass coalesced CSR build
    binsort_kernel<<<dim3(160, 2), 256, 0, stream>>>(
        adj_rows, adj_cols, adj_vals, adjT_rows, adjT_cols, adjT_vals,
        metaA, cntA, metaB, cntB);
    rowsort_kernel<<<dim3(NBUK, 2), 256, 0, stream>>>(
        metaA, cntA, sortedA, rpA, metaB, cntB, sortedB, rpB);

    // K = 2 PPR iterations (0.9 folded into vals), temporal A/B split
    spmm_kernel<<<10000, 256, 0, stream>>>(rpA, sortedA, X0s, X1s,
                                           rpB, sortedB, X0t, X1t);
    spmm_kernel<<<10000, 256, 0, stream>>>(rpA, sortedA, X1s, X2s,
                                           rpB, sortedB, X1t, X2t);

    combine_kernel<<<dim3(313, 4), 256, 0, stream>>>(X2s, X0s, X2t, X0t, hadBK);

    gemm1_kernel<<<dim3(8, NZ_), 512, 0, stream>>>(hadBK, W1, part);
    gemm23_kernel<<<B_, 256, 0, stream>>>(part, b1, W2, b2, W3, b3, out);
}

// Round 10
// 403.552 us; speedup vs baseline: 9.0677x; 1.0160x over previous
//
#include <hip/hip_runtime.h>
#include <hip/hip_fp16.h>

#define G_   20000
#define B_   256
#define NNZ_ 640000
#define KCH_ 640       // gemm1 split-K chunk (20 steps of 32; z=31 does 5)
#define NZ_  32        // split-K factor
#define NBUK 157       // ceil(20000/128) row buckets of 128 rows
#define BCAP 4608      // per-bucket segment capacity (avg 4076, >8 sigma slack)
#define EPB  4000      // binsort entries per block (160 blocks x 4000 = NNZ)

typedef float f4 __attribute__((ext_vector_type(4)));
typedef _Float16 h8 __attribute__((ext_vector_type(8)));

// ---------------- embed + transpose: [B,G] f32 -> [G,B] f16 --------------
// Block (0,0) also zeroes the binsort counters (saves a dispatch).
__global__ __launch_bounds__(256) void embed_kernel(
        const float* __restrict__ xsamp, const float* __restrict__ xtf,
        const float* __restrict__ em, const float* __restrict__ bm,
        const float* __restrict__ ee, const float* __restrict__ be,
        __half* __restrict__ X0s, __half* __restrict__ X0t,
        int* __restrict__ cnt) {
    __shared__ float lds[64][65];       // [b][g]
    const int t  = threadIdx.x;
    if (blockIdx.x == 0 && blockIdx.y == 0)
        for (int i = t; i < 2 * NBUK; i += 256) cnt[i] = 0;
    const int gb = blockIdx.x * 64, bb = blockIdx.y * 64;
    const float a_m = em[0], c_m = bm[0], a_e = ee[0], c_e = be[0];
    const int gl = t & 63, brow0 = t >> 6;     // load mapping
    const int cl = t & 31, row0  = t >> 5;     // store mapping
    const int g_l = gb + gl;
#pragma unroll
    for (int r = 0; r < 16; r++) {
        int bl = brow0 + r * 4;
        float v = 0.f;
        if (g_l < G_) v = xsamp[(size_t)(bb + bl) * G_ + g_l];
        lds[bl][gl] = fmaxf(a_m * v + c_m, 0.f);
    }
    __syncthreads();
#pragma unroll
    for (int r = 0; r < 8; r++) {
        int gl2 = row0 + r * 8;
        int g = gb + gl2;
        if (g < G_) {
            __half2 hv = __floats2half2_rn(lds[cl * 2][gl2], lds[cl * 2 + 1][gl2]);
            *(__half2*)(X0s + (size_t)g * B_ + bb + cl * 2) = hv;
        }
    }
    __syncthreads();
#pragma unroll
    for (int r = 0; r < 16; r++) {
        int bl = brow0 + r * 4;
        float v = 0.f;
        if (g_l < G_) v = xtf[(size_t)(bb + bl) * G_ + g_l];
        lds[bl][gl] = fmaxf(a_e * v + c_e, 0.f);
    }
    __syncthreads();
#pragma unroll
    for (int r = 0; r < 8; r++) {
        int gl2 = row0 + r * 8;
        int g = gb + gl2;
        if (g < G_) {
            __half2 hv = __floats2half2_rn(lds[cl * 2][gl2], lds[cl * 2 + 1][gl2]);
            *(__half2*)(X0t + (size_t)g * B_ + bb + cl * 2) = hv;
        }
    }
}

// ---------------- pass 1: bucket sort COO into 128-row bins --------------
// meta.x = (rowInBucket<<24) | col*512 ; meta.y = f32 bits of 0.9*val.
__global__ __launch_bounds__(256) void binsort_kernel(
        const int* __restrict__ rA, const int* __restrict__ cA, const float* __restrict__ vA,
        const int* __restrict__ rB, const int* __restrict__ cB, const float* __restrict__ vB,
        int2* __restrict__ metaA, int* __restrict__ cntA,
        int2* __restrict__ metaB, int* __restrict__ cntB) {
    __shared__ int2 stage[EPB];                 // 32000 B
    __shared__ unsigned char bkid[EPB];         // 4000 B
    __shared__ int hist[NBUK], lstart[NBUK], gbase[NBUK];
    const int t = threadIdx.x;
    const int base = blockIdx.x * EPB;
    const int* rows; const int* colsp; const float* valsp; int2* meta; int* cnt;
    if (blockIdx.y == 0) { rows = rA; colsp = cA; valsp = vA; meta = metaA; cnt = cntA; }
    else                 { rows = rB; colsp = cB; valsp = vB; meta = metaB; cnt = cntB; }

    for (int i = t; i < NBUK; i += 256) hist[i] = 0;
    __syncthreads();
    for (int i = t; i < EPB; i += 256)
        atomicAdd(&hist[rows[base + i] >> 7], 1);
    __syncthreads();
    if (t == 0) {
        int s = 0;
        for (int b = 0; b < NBUK; b++) { lstart[b] = s; s += hist[b]; }
    }
    __syncthreads();
    if (t < NBUK) hist[t] = lstart[t];          // reuse hist as cursor
    __syncthreads();
    for (int i = t; i < EPB; i += 256) {
        int r = rows[base + i];
        int c = colsp[base + i];
        float v = valsp[base + i];
        int b = r >> 7;
        int p = atomicAdd(&hist[b], 1);
        stage[p] = make_int2(((r & 127) << 24) | (c * (B_ * 2)),
                             __float_as_int(0.9f * v));
        bkid[p] = (unsigned char)b;
    }
    __syncthreads();
    if (t < NBUK) gbase[t] = atomicAdd(&cnt[t], hist[t] - lstart[t]);
    __syncthreads();
    for (int i = t; i < EPB; i += 256) {
        int b = bkid[i];
        meta[(size_t)b * BCAP + gbase[b] + (i - lstart[b])] = stage[i];
    }
}

// ---------------- pass 2: in-bucket counting sort -> exact CSR -----------
__global__ __launch_bounds__(256) void rowsort_kernel(
        const int2* __restrict__ metaA, const int* __restrict__ cntA,
        int2* __restrict__ sortedA, int* __restrict__ rpA,
        const int2* __restrict__ metaB, const int* __restrict__ cntB,
        int2* __restrict__ sortedB, int* __restrict__ rpB) {
    __shared__ int2 stage[BCAP];                // 36864 B
    __shared__ int2 sorted[BCAP];               // 36864 B
    __shared__ int carr[NBUK];
    __shared__ int hist[128], lstart[128];
    const int t = threadIdx.x;
    const int buk = blockIdx.x;
    const int2* meta; const int* cnt; int2* outp; int* rp;
    if (blockIdx.y == 0) { meta = metaA; cnt = cntA; outp = sortedA; rp = rpA; }
    else                 { meta = metaB; cnt = cntB; outp = sortedB; rp = rpB; }

    if (t < NBUK) carr[t] = cnt[t];
    if (t < 128) hist[t] = 0;
    __syncthreads();
    int bukStart = 0;
    const int nE = carr[buk];
    for (int b = 0; b < buk; b++) bukStart += carr[b];

    const int2* mp = meta + (size_t)buk * BCAP;
    for (int i = t; i < nE; i += 256) {
        int2 m = mp[i];
        stage[i] = m;
        atomicAdd(&hist[(unsigned)m.x >> 24], 1);
    }
    __syncthreads();
    if (t == 0) {
        int s = 0;
        for (int r = 0; r < 128; r++) { lstart[r] = s; s += hist[r]; }
    }
    __syncthreads();
    if (t < 128) hist[t] = lstart[t];           // reuse as cursor
    __syncthreads();
    for (int i = t; i < nE; i += 256) {
        int2 m = stage[i];
        int r = (unsigned)m.x >> 24;
        int p = atomicAdd(&hist[r], 1);
        sorted[p] = make_int2(m.x & 0xFFFFFF, m.y);
    }
    __syncthreads();
    for (int i = t; i < nE; i += 256)
        outp[bukStart + i] = sorted[i];
    if (t < 128) {
        int g = buk * 128 + t;
        if (g < G_) rp[g] = bukStart + lstart[t];
    }
    if (buk == NBUK - 1 && t == 0) rp[G_] = bukStart + nE;
}

// ---------------- SPMM f16, full row/wave, 16-deep gather MLP ------------
// grid 10000; combo = bid&1 -> matrix (round-robin i%8 parity-locks each
// XCD to one matrix's x). Wave owns row g; n wave-uniform (no predication).
__global__ __launch_bounds__(256) void spmm_kernel(
        const int* __restrict__ rpA, const int2* __restrict__ metaA,
        const __half* __restrict__ xinA, __half* __restrict__ xoutA,
        const int* __restrict__ rpB, const int2* __restrict__ metaB,
        const __half* __restrict__ xinB, __half* __restrict__ xoutB) {
    const int bid   = blockIdx.x;
    const int combo = bid & 1;
    const int t = threadIdx.x;
    const int wave = t >> 6, lane = t & 63;
    const int g = (bid >> 1) * 4 + wave;
    const int* rp; const int2* meta; const __half* xin; __half* xout;
    if (combo == 0) { rp = rpA; meta = metaA; xin = xinA; xout = xoutA; }
    else            { rp = rpB; meta = metaB; xin = xinB; xout = xoutB; }
    const int beg = __builtin_amdgcn_readfirstlane(rp[g]);
    const int n   = __builtin_amdgcn_readfirstlane(rp[g + 1]) - beg;
    const int2* mp = meta + beg;
    const char* xb = (const char*)xin + lane * 8;
    float a0 = 0.f, a1 = 0.f, a2 = 0.f, a3 = 0.f;
    int e = 0;
    for (; e + 16 <= n; e += 16) {
        int2 m[16];
        uint2 r[16];
#pragma unroll
        for (int j = 0; j < 16; j++) m[j] = mp[e + j];
#pragma unroll
        for (int j = 0; j < 16; j++) r[j] = *(const uint2*)(xb + m[j].x);
#pragma unroll
        for (int j = 0; j < 16; j++) {
            float v = __int_as_float(m[j].y);
            float2 l = __half22float2(*(__half2*)&r[j].x);
            float2 h = __half22float2(*(__half2*)&r[j].y);
            a0 = fmaf(v, l.x, a0); a1 = fmaf(v, l.y, a1);
            a2 = fmaf(v, h.x, a2); a3 = fmaf(v, h.y, a3);
        }
    }
    if (e + 8 <= n) {
        int2 m[8];
        uint2 r[8];
#pragma unroll
        for (int j = 0; j < 8; j++) m[j] = mp[e + j];
#pragma unroll
        for (int j = 0; j < 8; j++) r[j] = *(const uint2*)(xb + m[j].x);
#pragma unroll
        for (int j = 0; j < 8; j++) {
            float v = __int_as_float(m[j].y);
            float2 l = __half22float2(*(__half2*)&r[j].x);
            float2 h = __half22float2(*(__half2*)&r[j].y);
            a0 = fmaf(v, l.x, a0); a1 = fmaf(v, l.y, a1);
            a2 = fmaf(v, h.x, a2); a3 = fmaf(v, h.y, a3);
        }
        e += 8;
    }
    if (e + 4 <= n) {
        int2 m[4];
        uint2 r[4];
#pragma unroll
        for (int j = 0; j < 4; j++) m[j] = mp[e + j];
#pragma unroll
        for (int j = 0; j < 4; j++) r[j] = *(const uint2*)(xb + m[j].x);
#pragma unroll
        for (int j = 0; j < 4; j++) {
            float v = __int_as_float(m[j].y);
            float2 l = __half22float2(*(__half2*)&r[j].x);
            float2 h = __half22float2(*(__half2*)&r[j].y);
            a0 = fmaf(v, l.x, a0); a1 = fmaf(v, l.y, a1);
            a2 = fmaf(v, h.x, a2); a3 = fmaf(v, h.y, a3);
        }
        e += 4;
    }
    for (; e < n; ++e) {
        int2 m = mp[e];
        float v = __int_as_float(m.y);
        uint2 r = *(const uint2*)(xb + m.x);
        float2 l = __half22float2(*(__half2*)&r.x), h = __half22float2(*(__half2*)&r.y);
        a0 = fmaf(v, l.x, a0); a1 = fmaf(v, l.y, a1);
        a2 = fmaf(v, h.x, a2); a3 = fmaf(v, h.y, a3);
    }
    __half2 o0 = __floats2half2_rn(a0, a1);
    __half2 o1 = __floats2half2_rn(a2, a3);
    uint2 ov;
    ov.x = *(unsigned*)&o0;
    ov.y = *(unsigned*)&o1;
    *(uint2*)((char*)xout + (size_t)g * (B_ * 2) + lane * 8) = ov;
}

// ---------------- combine + transpose + f16: -> had[b][g] ----------------
__global__ __launch_bounds__(256) void combine_kernel(
        const __half* __restrict__ X2s, const __half* __restrict__ X0s,
        const __half* __restrict__ X2t, const __half* __restrict__ X0t,
        __half* __restrict__ hadBK) {
    __shared__ float lds[64][65];       // [g][b]
    const int t = threadIdx.x;
    const int gb = blockIdx.x * 64, bb = blockIdx.y * 64;
    const int cl = t & 31, row0 = t >> 5;
#pragma unroll
    for (int r = 0; r < 8; r++) {
        int gl = row0 + r * 8;
        int g = gb + gl;
        float px = 0.f, py = 0.f;
        if (g < G_) {
            size_t idx = (size_t)g * B_ + bb + cl * 2;
            float2 x2s = __half22float2(*(const __half2*)(X2s + idx));
            float2 x0s = __half22float2(*(const __half2*)(X0s + idx));
            float2 x2t = __half22float2(*(const __half2*)(X2t + idx));
            float2 x0t = __half22float2(*(const __half2*)(X0t + idx));
            px = (x2s.x + 0.1f * x0s.x) * (x2t.x + 0.1f * x0t.x);
            py = (x2s.y + 0.1f * x0s.y) * (x2t.y + 0.1f * x0t.y);
        }
        lds[gl][cl * 2]     = px;
        lds[gl][cl * 2 + 1] = py;
    }
    __syncthreads();
#pragma unroll
    for (int r = 0; r < 8; r++) {
        int bl = row0 + r * 8;
        int g0 = gb + cl * 2;
        if (g0 < G_) {
            __half2 hv = __floats2half2_rn(lds[cl * 2][bl], lds[cl * 2 + 1][bl]);
            *(__half2*)(hadBK + (size_t)(bb + bl) * G_ + g0) = hv;
        }
    }
}

// ---------------- GEMM1 MFMA f16, dbuf LDS, XCD-affine z-grouping --------
// Linear grid 256. Decode keeps all 8 o-blocks of a split-K chunk z on ONE
// XCD (round-robin i%8): the 327KB hadBK z-slice is fetched once per XCD
// and L2-reused 8x (was 8 XCDs x refetch = 8x traffic).
__global__ __launch_bounds__(512) void gemm1_kernel(
        const __half* __restrict__ hadBK, const float* __restrict__ W1,
        float* __restrict__ part) {
    __shared__ _Float16 a_lds[2][256][40];   // 40960 B
    __shared__ _Float16 b_lds[2][128][40];   // 20480 B
    const int lid = blockIdx.x;
    const int xcd = lid & 7, jj = lid >> 3;
    const int zz = xcd + 8 * (jj & 3);       // split-K chunk 0..31
    const int oo = jj >> 2;                  // o-block 0..7
    const int t = threadIdx.x;
    const int lane = t & 63, wid = t >> 6;
    const int wm = wid >> 1, wn = wid & 1;
    const int l15 = lane & 15, l4 = lane >> 4;
    const int ob = oo * 128;
    const int kb = zz * KCH_;
    int kend = kb + KCH_; if (kend > G_) kend = G_;
    const int nsteps = (kend - kb) >> 5;       // 20, or 5 at z=31
    const int ar = t >> 1, ah = t & 1;
    const int br = t >> 2, bs = t & 3;
    const _Float16* hadH = (const _Float16*)hadBK;
    const _Float16* asrc = hadH + (size_t)ar * G_ + ah * 16;
    const float*    bsrc = W1 + (size_t)(ob + br) * G_ + bs * 8;
    f4 acc[4][4] = {};
    h8 ra0 = *(const h8*)(asrc + kb);
    h8 ra1 = *(const h8*)(asrc + kb + 8);
    f4 rb0 = *(const f4*)(bsrc + kb);
    f4 rb1 = *(const f4*)(bsrc + kb + 4);
    *(h8*)&a_lds[0][ar][ah * 16]     = ra0;
    *(h8*)&a_lds[0][ar][ah * 16 + 8] = ra1;
    {
        h8 h;
        h[0] = (_Float16)rb0[0]; h[1] = (_Float16)rb0[1];
        h[2] = (_Float16)rb0[2]; h[3] = (_Float16)rb0[3];
        h[4] = (_Float16)rb1[0]; h[5] = (_Float16)rb1[1];
        h[6] = (_Float16)rb1[2]; h[7] = (_Float16)rb1[3];
        *(h8*)&b_lds[0][br][bs * 8] = h;
    }
    __syncthreads();
    int p = 0;
    for (int s = 0; s < nsteps; ++s) {
        if (s + 1 < nsteps) {
            const int k1 = kb + (s + 1) * 32;
            ra0 = *(const h8*)(asrc + k1);
            ra1 = *(const h8*)(asrc + k1 + 8);
            rb0 = *(const f4*)(bsrc + k1);
            rb1 = *(const f4*)(bsrc + k1 + 4);
        }
        h8 af[4], bf[4];
#pragma unroll
        for (int m = 0; m < 4; m++)
            af[m] = *(const h8*)&a_lds[p][wm * 64 + m * 16 + l15][l4 * 8];
#pragma unroll
        for (int n = 0; n < 4; n++)
            bf[n] = *(const h8*)&b_lds[p][wn * 64 + n * 16 + l15][l4 * 8];
#pragma unroll
        for (int m = 0; m < 4; m++)
#pragma unroll
            for (int n = 0; n < 4; n++)
                acc[m][n] = __builtin_amdgcn_mfma_f32_16x16x32_f16(
                    af[m], bf[n], acc[m][n], 0, 0, 0);
        if (s + 1 < nsteps) {
            *(h8*)&a_lds[p ^ 1][ar][ah * 16]     = ra0;
            *(h8*)&a_lds[p ^ 1][ar][ah * 16 + 8] = ra1;
            h8 h;
            h[0] = (_Float16)rb0[0]; h[1] = (_Float16)rb0[1];
            h[2] = (_Float16)rb0[2]; h[3] = (_Float16)rb0[3];
            h[4] = (_Float16)rb1[0]; h[5] = (_Float16)rb1[1];
            h[6] = (_Float16)rb1[2]; h[7] = (_Float16)rb1[3];
            *(h8*)&b_lds[p ^ 1][br][bs * 8] = h;
            __syncthreads();
            p ^= 1;
        }
    }
    const size_t zoff = (size_t)zz * (B_ * 1024);
#pragma unroll
    for (int m = 0; m < 4; m++)
#pragma unroll
        for (int n = 0; n < 4; n++)
#pragma unroll
            for (int j = 0; j < 4; j++) {
                int b = wm * 64 + m * 16 + l4 * 4 + j;
                int o = ob + wn * 64 + n * 16 + l15;
                part[zoff + (size_t)b * 1024 + o] = acc[m][n][j];
            }
}

// ---------------- fused reduce+bias+relu + GEMM2 (relu) + GEMM3 ----------
__global__ __launch_bounds__(256) void gemm23_kernel(
        const float* __restrict__ part, const float* __restrict__ b1,
        const float* __restrict__ W2, const float* __restrict__ b2,
        const float* __restrict__ W3, const float* __restrict__ b3,
        float* __restrict__ out) {
    __shared__ float h1row[1024];
    __shared__ float h2p[2][128];
    const int b = blockIdx.x, t = threadIdx.x;
    {   // split-K reduce: h1row = relu(sum_z part[z][b][:] + b1)
        f4 s = {0.f, 0.f, 0.f, 0.f};
        const float* pb = part + (size_t)b * 1024;
        for (int z = 0; z < NZ_; z++)
            s += ((const f4*)(pb + (size_t)z * 262144))[t];
        s += ((const f4*)b1)[t];
        f4 r;
        r[0] = fmaxf(s[0], 0.f); r[1] = fmaxf(s[1], 0.f);
        r[2] = fmaxf(s[2], 0.f); r[3] = fmaxf(s[3], 0.f);
        ((f4*)h1row)[t] = r;
    }
    __syncthreads();
    {   // GEMM2: output o = t&127, k-half = t>>7
        const int o = t & 127, hh = t >> 7;
        float acc = 0.f;
        const f4* w  = (const f4*)(W2 + (size_t)o * 1024 + hh * 512);
        const f4* hr = (const f4*)(h1row + hh * 512);
        for (int k = 0; k < 128; k++) {
            f4 wv = w[k], hv = hr[k];
            acc += wv[0] * hv[0] + wv[1] * hv[1] + wv[2] * hv[2] + wv[3] * hv[3];
        }
        h2p[hh][o] = acc;
    }
    __syncthreads();
    if (t < 128) h2p[0][t] = fmaxf(h2p[0][t] + h2p[1][t] + b2[t], 0.f);
    __syncthreads();
    if (t < 33) {
        float acc = b3[t];
        const f4* w  = (const f4*)(W3 + (size_t)t * 128);
        const f4* hv = (const f4*)h2p[0];
#pragma unroll
        for (int k = 0; k < 32; k++) {
            f4 a = w[k], x = hv[k];
            acc += a[0] * x[0] + a[1] * x[1] + a[2] * x[2] + a[3] * x[3];
        }
        out[b * 33 + t] = acc;
    }
}

extern "C" void kernel_launch(void* const* d_in, const int* in_sizes, int n_in,
                              void* d_out, int out_size, void* d_ws, size_t ws_size,
                              hipStream_t stream) {
    const float* x_sample  = (const float*)d_in[0];
    const float* x_TF      = (const float*)d_in[1];
    const int*   adj_rows  = (const int*)d_in[2];
    const int*   adj_cols  = (const int*)d_in[3];
    const float* adj_vals  = (const float*)d_in[4];
    const int*   adjT_rows = (const int*)d_in[5];
    const int*   adjT_cols = (const int*)d_in[6];
    const float* adjT_vals = (const float*)d_in[7];
    const float* emb_mut   = (const float*)d_in[8];
    const float* bias_mut  = (const float*)d_in[9];
    const float* emb_exp   = (const float*)d_in[10];
    const float* bias_exp  = (const float*)d_in[11];
    const float* W1 = (const float*)d_in[12];
    const float* b1 = (const float*)d_in[13];
    const float* W2 = (const float*)d_in[14];
    const float* b2 = (const float*)d_in[15];
    const float* W3 = (const float*)d_in[16];
    const float* b3 = (const float*)d_in[17];
    float* out = (float*)d_out;

    // ---- workspace layout (~120 MB) ----
    char* w = (char*)d_ws;
    auto alloc = [&](size_t bytes) {
        char* p = w; w += (bytes + 255) & ~(size_t)255; return p;
    };
    __half* X0s = (__half*)alloc(5120000 * 2);
    __half* X1s = (__half*)alloc(5120000 * 2);
    __half* X2s = (__half*)alloc(5120000 * 2);
    __half* X0t = (__half*)alloc(5120000 * 2);
    __half* X1t = (__half*)alloc(5120000 * 2);
    __half* X2t = (__half*)alloc(5120000 * 2);
    float*  part = (float*)alloc((size_t)NZ_ * 262144 * 4);   // 33.5 MB
    int2*   metaA   = (int2*)alloc((size_t)NBUK * BCAP * 8);  // 5.79 MB bucketed
    int2*   metaB   = (int2*)alloc((size_t)NBUK * BCAP * 8);
    int2*   sortedA = (int2*)alloc((size_t)(NNZ_ + 128) * 8); // 5.12 MB CSR-sorted
    int2*   sortedB = (int2*)alloc((size_t)(NNZ_ + 128) * 8);
    int*    cnt   = (int*)alloc(2 * NBUK * 4);
    int*    cntA  = cnt;
    int*    cntB  = cnt + NBUK;
    int*    rpA   = (int*)alloc(20001 * 4);
    int*    rpB   = (int*)alloc(20001 * 4);
    __half* hadBK = X1s;    // overlay: X1s dead after spmm iter 2

    // embed also zeroes cnt (block (0,0))
    embed_kernel<<<dim3(313, 4), 256, 0, stream>>>(
        x_sample, x_TF, emb_mut, bias_mut, emb_exp, bias_exp, X0s, X0t, cnt);

    // two-pass coalesced CSR build
    binsort_kernel<<<dim3(160, 2), 256, 0, stream>>>(
        adj_rows, adj_cols, adj_vals, adjT_rows, adjT_cols, adjT_vals,
        metaA, cntA, metaB, cntB);
    rowsort_kernel<<<dim3(NBUK, 2), 256, 0, stream>>>(
        metaA, cntA, sortedA, rpA, metaB, cntB, sortedB, rpB);

    // K = 2 PPR iterations (0.9 folded into vals)
    spmm_kernel<<<10000, 256, 0, stream>>>(rpA, sortedA, X0s, X1s,
                                           rpB, sortedB, X0t, X1t);
    spmm_kernel<<<10000, 256, 0, stream>>>(rpA, sortedA, X1s, X2s,
                                           rpB, sortedB, X1t, X2t);

    combine_kernel<<<dim3(313, 4), 256, 0, stream>>>(X2s, X0s, X2t, X0t, hadBK);

    gemm1_kernel<<<256, 512, 0, stream>>>(hadBK, W1, part);
    gemm23_kernel<<<B_, 256, 0, stream>>>(part, b1, W2, b2, W3, b3, out);
}